// Round 11
// baseline (399.243 us; speedup 1.0000x reference)
//
#include <hip/hip_runtime.h>
#include <hip/hip_bf16.h>

// Problem constants
#define BB 8
#define NN 1024
#define DD 256
#define HH 8
#define DK 32
#define FFN 1024
#define NLAYERS 4
#define MM (BB * NN)          // 8192 rows
#define ROW_ELEMS (MM * DD)   // 2,097,152

// 1/sqrt(32) * log2(e)  (log2e folded so attention uses native exp2)
#define QSCALE 0.2550655192922103f
#define LOG2E  1.4426950408889634f

typedef unsigned short ushort_t;
typedef __attribute__((ext_vector_type(8))) short bf16x8;
typedef __attribute__((ext_vector_type(4))) short bf16x4;
typedef __attribute__((ext_vector_type(4))) float f32x4;

// K=16 bf16 MFMA: builtin if present on device; inline-asm fallback; host stub.
__device__ __forceinline__ f32x4 mfma16(bf16x4 a, bf16x4 b, f32x4 c) {
#if __has_builtin(__builtin_amdgcn_mfma_f32_16x16x16bf16_1k)
    return __builtin_amdgcn_mfma_f32_16x16x16bf16_1k(a, b, c, 0, 0, 0);
#elif defined(__AMDGCN__)
    f32x4 d;
    asm volatile("v_mfma_f32_16x16x16_bf16 %0, %1, %2, %3"
                 : "=v"(d)
                 : "v"(a), "v"(b), "v"(c));
    return d;
#else
    return c;  // host-pass stub
#endif
}

__device__ __forceinline__ ushort_t f2b(float f) {
    __hip_bfloat16 h = __float2bfloat16(f);
    return *reinterpret_cast<ushort_t*>(&h);
}

// raw v_exp_f32 (input already in log2 domain) — avoids any OCML wrapper
__device__ __forceinline__ float fast_exp2(float x) {
#if __has_builtin(__builtin_amdgcn_exp2f)
    return __builtin_amdgcn_exp2f(x);
#else
    return exp2f(x);
#endif
}

// async global -> LDS, 16 B per lane. LDS dest = wave-uniform base + lane*16B.
__device__ __forceinline__ void async_ld16(const void* g, void* l) {
    __builtin_amdgcn_global_load_lds((const __attribute__((address_space(1))) void*)g,
                                     (__attribute__((address_space(3))) void*)l, 16, 0, 0);
}

// counted-vmcnt pipeline barrier (T3+T4): each wave waits its OWN prev-step
// stage loads (4/thread) before the barrier, leaving the newest 4 in flight
// across it. lgkmcnt(0) publishes ds_writes. Extra vmem in compute phases
// (bias loads, scatter stores) only OVER-waits (needed stage is always older
// than the newest 4) — never under-waits. sched_barrier(0) per rule #18.
__device__ __forceinline__ void pipe_barrier4() {
#if defined(__AMDGCN__)
    asm volatile("s_waitcnt vmcnt(4) lgkmcnt(0)" ::: "memory");
#endif
    __builtin_amdgcn_s_barrier();
    __builtin_amdgcn_sched_barrier(0);
}
__device__ __forceinline__ void pipe_barrier0() {
#if defined(__AMDGCN__)
    asm volatile("s_waitcnt vmcnt(0) lgkmcnt(0)" ::: "memory");
#endif
    __builtin_amdgcn_s_barrier();
    __builtin_amdgcn_sched_barrier(0);
}

// ---------------------------------------------------------------------------
// copy-in + qkext fused: x -> xf (f32) + xb (bf16), float4-vectorized.
// Blocks [0,256) additionally write the layer-invariant Q/K ext columns.
// ---------------------------------------------------------------------------
__global__ __launch_bounds__(256) void copy_in_kernel(const float4* __restrict__ in,
                                                      float4* __restrict__ xf,
                                                      ushort4* __restrict__ xb, int n4,
                                                      const float* __restrict__ coords,
                                                      ushort_t* __restrict__ Qa,
                                                      ushort_t* __restrict__ Ka) {
    int i = blockIdx.x * 256 + threadIdx.x;
    if (i < n4) {
        float4 v = in[i];
        xf[i] = v;
        ushort4 b = {f2b(v.x), f2b(v.y), f2b(v.z), f2b(v.w)};
        xb[i] = b;
    }
    if (blockIdx.x < 256) {
        const int id = blockIdx.x * 256 + threadIdx.x;   // 0..65535 = bh*1024 + n
        const int bh = id >> 10, n = id & 1023;
        const int b = bh >> 3;
        ushort_t buf[32];
#pragma unroll
        for (int d = 0; d < 32; ++d) buf[d] = 0;
        buf[0] = f2b(coords[(size_t)(b * NN + n) * 3 + 0]);
        buf[1] = f2b(coords[(size_t)(b * NN + n) * 3 + 1]);
        buf[2] = f2b(coords[(size_t)(b * NN + n) * 3 + 2]);
        ushort_t* kp = Ka + ((size_t)bh * NN + n) * 64 + 32;
        ushort_t* qp = Qa + ((size_t)bh * NN + n) * 64 + 32;
        const uint4* b4 = (const uint4*)buf;
        uint4 z4 = {0u, 0u, 0u, 0u};
#pragma unroll
        for (int c = 0; c < 4; ++c) {
            *(uint4*)(kp + c * 8) = b4[c];
            *(uint4*)(qp + c * 8) = z4;
        }
    }
}

// ---------------------------------------------------------------------------
// Fused weight prep (one dispatch): 5 transposes + bias concat.
// ---------------------------------------------------------------------------
__global__ __launch_bounds__(256) void prep_kernel(const float* __restrict__ Wq,
                                                   const float* __restrict__ Wk,
                                                   const float* __restrict__ Wv,
                                                   const float* __restrict__ W1,
                                                   const float* __restrict__ W2,
                                                   const float* __restrict__ bq,
                                                   const float* __restrict__ bk,
                                                   const float* __restrict__ bv,
                                                   ushort_t* __restrict__ wqkvt,
                                                   ushort_t* __restrict__ w1t,
                                                   ushort_t* __restrict__ w2t,
                                                   float* __restrict__ bqkv) {
    const int id = blockIdx.x;
    const int layer = id / 707;
    const int r = id % 707;
    const int tid = threadIdx.x;

    if (r >= 704) {  // bias concat: 3 chunks of 256
        const int chunk = r - 704;
        const float* src = (chunk == 0) ? bq : (chunk == 1) ? bk : bv;
        bqkv[layer * 768 + chunk * 256 + tid] = src[layer * 256 + tid];
        return;
    }

    const float* src;
    ushort_t* dst;
    int R, C, x, y;
    if (r < 192) {
        const int w = r >> 6, rr = r & 63;
        src = ((w == 0) ? Wq : (w == 1) ? Wk : Wv) + (size_t)layer * 65536;
        dst = wqkvt + (size_t)layer * 196608 + w * 65536;
        R = 256; C = 256; x = rr & 7; y = rr >> 3;
    } else if (r < 448) {
        const int rr = r - 192;
        src = W1 + (size_t)layer * 262144;
        dst = w1t + (size_t)layer * 262144;
        R = 256; C = 1024; x = rr & 31; y = rr >> 5;
    } else {
        const int rr = r - 448;
        src = W2 + (size_t)layer * 262144;
        dst = w2t + (size_t)layer * 262144;
        R = 1024; C = 256; x = rr & 7; y = rr >> 3;
    }
    const int r0 = y * 32, c0 = x * 32;
    __shared__ float tile[32][33];
    const int tx = tid & 31, ty = tid >> 5;
#pragma unroll
    for (int i = 0; i < 4; ++i)
        tile[ty + 8 * i][tx] = src[(size_t)(r0 + ty + 8 * i) * C + (c0 + tx)];
    __syncthreads();
#pragma unroll
    for (int i = 0; i < 4; ++i)
        dst[(size_t)(c0 + ty + 8 * i) * R + (r0 + tx)] = f2b(tile[tx][ty + 8 * i]);
}

// ---------------------------------------------------------------------------
// MFMA bf16 GEMM, async global_load_lds staging (16B), BK=64, SPLIT-HALF LDS,
// double-buffered (R4-verified). MODE 2: QKV scatter into Qa/Ka/Vt.
// Used ONLY for layer 0's QKV (layers 1-3 fused into ffn_ln).
// ---------------------------------------------------------------------------
template <int MODE, int BM>
__global__ __launch_bounds__(256) void mfma_gemm_kernel(const ushort_t* __restrict__ A,
                                                        const ushort_t* __restrict__ Bt,
                                                        const float* __restrict__ bias,
                                                        void* __restrict__ C0,
                                                        void* __restrict__ C1,
                                                        void* __restrict__ C2,
                                                        const float* __restrict__ coords,
                                                        const float* __restrict__ alpha, int layer,
                                                        int K, int ldc) {
    constexpr int NI = BM / 32;
    __shared__ ushort_t As0[2][BM * 32];
    __shared__ ushort_t As1[2][BM * 32];
    __shared__ ushort_t Bs0[2][128 * 32];
    __shared__ ushort_t Bs1[2][128 * 32];

    const int t    = threadIdx.x;
    const int bm   = blockIdx.y * BM;
    const int bn   = blockIdx.x * 128;
    const int wave = t >> 6, lane = t & 63;
    const int wm   = (wave >> 1) * (BM / 2), wn = (wave & 1) * 64;
    const int quad = lane >> 4, l16 = lane & 15;

    const int srow = t >> 2;          // 0..63
    const int scol = (t & 3) * 8;     // 16B chunk within a 32-ushort half-row

    f32x4 acc[NI][4];
#pragma unroll
    for (int i = 0; i < NI; ++i)
#pragma unroll
        for (int j = 0; j < 4; ++j) {
            f32x4 z = {0.f, 0.f, 0.f, 0.f};
            acc[i][j] = z;
        }

    auto stage = [&](int pb, int k0) {
        // half 0 (k0 .. k0+31)
        async_ld16(A + (size_t)(bm + srow) * K + k0 + scol, As0[pb] + wave * 512);
        if constexpr (BM == 128)
            async_ld16(A + (size_t)(bm + 64 + srow) * K + k0 + scol, As0[pb] + 2048 + wave * 512);
        async_ld16(Bt + (size_t)(bn + srow) * K + k0 + scol, Bs0[pb] + wave * 512);
        async_ld16(Bt + (size_t)(bn + 64 + srow) * K + k0 + scol, Bs0[pb] + 2048 + wave * 512);
        // half 1 (k0+32 .. k0+63)
        async_ld16(A + (size_t)(bm + srow) * K + k0 + 32 + scol, As1[pb] + wave * 512);
        if constexpr (BM == 128)
            async_ld16(A + (size_t)(bm + 64 + srow) * K + k0 + 32 + scol, As1[pb] + 2048 + wave * 512);
        async_ld16(Bt + (size_t)(bn + srow) * K + k0 + 32 + scol, Bs1[pb] + wave * 512);
        async_ld16(Bt + (size_t)(bn + 64 + srow) * K + k0 + 32 + scol, Bs1[pb] + 2048 + wave * 512);
    };

    stage(0, 0);   // prologue
    int pb = 0;
    for (int k0 = 0; k0 < K; k0 += 64, pb ^= 1) {
        __syncthreads();   // drains vmcnt(0): buf[pb] valid; prev compute finished

        if (k0 + 64 < K) stage(pb ^ 1, k0 + 64);   // overlap with compute below

        bf16x8 af0[NI], af1[NI], bf0[4], bf1[4];
#pragma unroll
        for (int i = 0; i < NI; ++i) {
            af0[i] = *(const bf16x8*)(As0[pb] + (wm + i * 16 + l16) * 32 + quad * 8);
            af1[i] = *(const bf16x8*)(As1[pb] + (wm + i * 16 + l16) * 32 + quad * 8);
        }
#pragma unroll
        for (int j = 0; j < 4; ++j) {
            bf0[j] = *(const bf16x8*)(Bs0[pb] + (wn + j * 16 + l16) * 32 + quad * 8);
            bf1[j] = *(const bf16x8*)(Bs1[pb] + (wn + j * 16 + l16) * 32 + quad * 8);
        }
#pragma unroll
        for (int i = 0; i < NI; ++i)
#pragma unroll
            for (int j = 0; j < 4; ++j) {
                acc[i][j] = __builtin_amdgcn_mfma_f32_16x16x32_bf16(af0[i], bf0[j], acc[i][j], 0, 0, 0);
                acc[i][j] = __builtin_amdgcn_mfma_f32_16x16x32_bf16(af1[i], bf1[j], acc[i][j], 0, 0, 0);
            }
    }

    const float av = (MODE == 2) ? alpha[layer] : 0.f;

#pragma unroll
    for (int j = 0; j < 4; ++j) {
        const int col = bn + wn + j * 16 + l16;
        const float bsv = bias[col];
#pragma unroll
        for (int i = 0; i < NI; ++i) {
            const int row0 = bm + wm + i * 16 + quad * 4;
            if (MODE == 2) {
                const int bb2 = row0 >> 10, nn0 = row0 & 1023;
                const int which = col >> 8, rem = col & 255;
                const int h = rem >> 5, d = rem & 31;
                const size_t bh = (size_t)((bb2 << 3) + h);
                if (which == 2) {
                    ushort4 pk;
                    pk.x = f2b(acc[i][j][0] + bsv);
                    pk.y = f2b(acc[i][j][1] + bsv);
                    pk.z = f2b(acc[i][j][2] + bsv);
                    pk.w = f2b(acc[i][j][3] + bsv);
                    *(ushort4*)&((ushort_t*)C2)[(bh * DK + d) * NN + nn0] = pk;
                } else {
#pragma unroll
                    for (int r = 0; r < 4; ++r) {
                        const float v = acc[i][j][r] + bsv;
                        const int nn = nn0 + r;
                        if (which == 0) {
                            ((ushort_t*)C0)[(bh * NN + nn) * 64 + d] = f2b(v * QSCALE);
                            if (d < 3)
                                ((ushort_t*)C0)[(bh * NN + nn) * 64 + 32 + d] =
                                    f2b(av * LOG2E * coords[(size_t)(bb2 * NN + nn) * 3 + d]);
                        } else {
                            ((ushort_t*)C1)[(bh * NN + nn) * 64 + d] = f2b(v);
                            // ext cols pre-filled once (layer-invariant)
                        }
                    }
                }
            } else {
#pragma unroll
                for (int r = 0; r < 4; ++r) {
                    float v = acc[i][j][r] + bsv;
                    if (MODE == 0)
                        ((float*)C0)[(size_t)(row0 + r) * ldc + col] = v;
                    else
                        ((ushort_t*)C0)[(size_t)(row0 + r) * ldc + col] = f2b(fmaxf(v, 0.f));
                }
            }
        }
    }
}

// ---------------------------------------------------------------------------
// FULLY FUSED: addLN1 + FF1 (relu) + FF2 + residual + LN2 [+ next-layer QKV].
// BM=32 rows/block, grid 256 (1/CU), 512 threads (8 waves).
// R11: TRIPLE-BUFFERED B staging + counted-vmcnt pipeline (T3+T4). Loads
// issue 2 steps ahead; each step's barrier waits only the prev-step loads
// (vmcnt(4)) leaving the newest 4 in flight — the per-step full-drain that
// made R10's version latency-bound (MfmaUtil 9%) is gone. Extra vmem in
// compute (bias loads, QKV scatter stores) only over-waits — always safe.
// LDS refit to EXACTLY 160 KiB: Ha 16K + Asf 16K + Bs 3x16K x2 = 96K +
// Ya[32][256] 32K; redS/redQ alias Ha[0] (dead after last FF2 step).
// Arithmetic bit-identical to R10 (only the sync schedule changed).
// ---------------------------------------------------------------------------
template <int DO_QKV>
__global__ __launch_bounds__(512) void ffn_ln_kernel(const float* __restrict__ aout,
                                                     const float* __restrict__ xfin,
                                                     const ushort_t* __restrict__ W1t,
                                                     const ushort_t* __restrict__ W2t,
                                                     const float* __restrict__ g1,
                                                     const float* __restrict__ be1,
                                                     const float* __restrict__ b1,
                                                     const float* __restrict__ b2,
                                                     const float* __restrict__ g2,
                                                     const float* __restrict__ be2,
                                                     float* __restrict__ xout,
                                                     const ushort_t* __restrict__ Wqkvt,
                                                     const float* __restrict__ bqkv,
                                                     const float* __restrict__ coords,
                                                     const float* __restrict__ alpha, int qlayer,
                                                     ushort_t* __restrict__ Qa,
                                                     ushort_t* __restrict__ Ka,
                                                     ushort_t* __restrict__ Vt) {
    __shared__ ushort_t Ha[8][32][32];      // hidden chunk [kh][row][kc] 16 KB
    __shared__ ushort_t Asf[8][32][32];     // LN1-out / LN2-out bf16     16 KB
    __shared__ ushort_t Bs0[3][8192];       // B k-half 0, TRIPLE         48 KB
    __shared__ ushort_t Bs1[3][8192];       // B k-half 1, TRIPLE         48 KB
    __shared__ float Ya[32][256];           // LN1-out f32                32 KB
    // redS/redQ alias Ha[0] (2 KB) — Ha is dead after the last FF2 step.
    float* redS = (float*)&Ha[0][0][0];
    float* redQ = redS + 256;

    const int t = threadIdx.x;
    const int bm = blockIdx.x * 32;
    const int wave = t >> 6, lane = t & 63;
    const int quad = lane >> 4, l16 = lane & 15;
    const int wn = wave * 32;           // wave's 32-col slice
    const int scol = (t & 3) * 8;

    auto stageB1 = [&](int buf, int nc, int ks) {
        const int nbase = nc * 256;
        const int k0 = ks * 64;
#pragma unroll
        for (int c = 0; c < 2; ++c) {
            const int brow = nbase + c * 128 + (t >> 2);
            async_ld16(W1t + (size_t)brow * 256 + k0 + scol, Bs0[buf] + c * 4096 + wave * 512);
            async_ld16(W1t + (size_t)brow * 256 + k0 + 32 + scol, Bs1[buf] + c * 4096 + wave * 512);
        }
    };
    auto stageB2 = [&](int buf, int nc, int ks) {
        const int k0 = nc * 256 + ks * 64;
#pragma unroll
        for (int c = 0; c < 2; ++c) {
            const int brow = c * 128 + (t >> 2);
            async_ld16(W2t + (size_t)brow * 1024 + k0 + scol, Bs0[buf] + c * 4096 + wave * 512);
            async_ld16(W2t + (size_t)brow * 1024 + k0 + 32 + scol, Bs1[buf] + c * 4096 + wave * 512);
        }
    };
    auto stageFFN = [&](int buf, int st) {
        const int group = st >> 2, ks = st & 3, nc = group >> 1;
        if (!(group & 1)) stageB1(buf, nc, ks);
        else stageB2(buf, nc, ks);
    };
    auto stageQKV = [&](int buf, int qst) {
        const int chunk = qst >> 2, ks = qst & 3;
#pragma unroll
        for (int c = 0; c < 2; ++c) {
            const int brow = chunk * 256 + c * 128 + (t >> 2);
            async_ld16(Wqkvt + (size_t)brow * 256 + ks * 64 + scol, Bs0[buf] + c * 4096 + wave * 512);
            async_ld16(Wqkvt + (size_t)brow * 256 + ks * 64 + 32 + scol, Bs1[buf] + c * 4096 + wave * 512);
        }
    };

    // prologue: 2 steps in flight before phase-0 compute (covers their latency)
    stageFFN(0, 0);
    stageFFN(1, 1);

    // ---- phase 0: LN1 = addln replica; 4 rows per wave ----
#pragma unroll
    for (int rr = 0; rr < 4; ++rr) {
        const int row = wave * 4 + rr;
        const size_t base = (size_t)(bm + row) * DD + lane * 4;

        float4 xv = *(const float4*)(xfin + base);
        float4 dl = *(const float4*)(aout + base);
        float v0 = xv.x + dl.x, v1 = xv.y + dl.y, v2 = xv.z + dl.z, v3 = xv.w + dl.w;

        float s = v0 + v1 + v2 + v3;
#pragma unroll
        for (int off = 32; off; off >>= 1) s += __shfl_xor(s, off);
        const float mean = s * (1.0f / 256.0f);

        float d0 = v0 - mean, d1 = v1 - mean, d2 = v2 - mean, d3 = v3 - mean;
        float s2 = d0 * d0 + d1 * d1 + d2 * d2 + d3 * d3;
#pragma unroll
        for (int off = 32; off; off >>= 1) s2 += __shfl_xor(s2, off);
        const float rs = rsqrtf(s2 * (1.0f / 256.0f) + 1e-5f);

        float4 gv = *(const float4*)(g1 + lane * 4);
        float4 bv = *(const float4*)(be1 + lane * 4);
        float y0 = d0 * rs * gv.x + bv.x;
        float y1 = d1 * rs * gv.y + bv.y;
        float y2 = d2 * rs * gv.z + bv.z;
        float y3 = d3 * rs * gv.w + bv.w;

        float4 yv = {y0, y1, y2, y3};
        *(float4*)&Ya[row][lane * 4] = yv;
        const int col0 = lane * 4;
        ushort4 yb = {f2b(y0), f2b(y1), f2b(y2), f2b(y3)};
        *(ushort4*)&Asf[col0 >> 5][row][col0 & 31] = yb;
    }

    f32x4 acc1[2][2], acc2[2][2];
#pragma unroll
    for (int i = 0; i < 2; ++i)
#pragma unroll
        for (int j = 0; j < 2; ++j) {
            f32x4 z = {0.f, 0.f, 0.f, 0.f};
            acc1[i][j] = z;
            acc2[i][j] = z;
        }

    // ---- 32 pipelined steps: [FF1 chunk nc (4), FF2 part nc (4)] x 4 ----
    for (int st = 0; st < 32; ++st) {
        if (!DO_QKV && st == 31) pipe_barrier0();   // nothing newer to keep in flight
        else pipe_barrier4();                       // buf[st%3] valid; newest 4 in flight

        const int nxt = st + 2;
        if (nxt < 32) stageFFN(nxt % 3, nxt);
        else if (DO_QKV && nxt < 34) stageQKV(nxt % 3, nxt - 32);

        const int buf = st % 3;
        const int group = st >> 2, ks = st & 3;
        const bool ff1 = !(group & 1);

        bf16x8 af0[2], af1[2], bf0[2], bf1[2];
#pragma unroll
        for (int i = 0; i < 2; ++i) {
            if (ff1) {
                af0[i] = *(const bf16x8*)&Asf[2 * ks][i * 16 + l16][quad * 8];
                af1[i] = *(const bf16x8*)&Asf[2 * ks + 1][i * 16 + l16][quad * 8];
            } else {
                af0[i] = *(const bf16x8*)&Ha[2 * ks][i * 16 + l16][quad * 8];
                af1[i] = *(const bf16x8*)&Ha[2 * ks + 1][i * 16 + l16][quad * 8];
            }
        }
#pragma unroll
        for (int j = 0; j < 2; ++j) {
            bf0[j] = *(const bf16x8*)(Bs0[buf] + (wn + j * 16 + l16) * 32 + quad * 8);
            bf1[j] = *(const bf16x8*)(Bs1[buf] + (wn + j * 16 + l16) * 32 + quad * 8);
        }

        if (ff1) {
#pragma unroll
            for (int i = 0; i < 2; ++i)
#pragma unroll
                for (int j = 0; j < 2; ++j) {
                    acc1[i][j] = __builtin_amdgcn_mfma_f32_16x16x32_bf16(af0[i], bf0[j], acc1[i][j], 0, 0, 0);
                    acc1[i][j] = __builtin_amdgcn_mfma_f32_16x16x32_bf16(af1[i], bf1[j], acc1[i][j], 0, 0, 0);
                }
            if (ks == 3) {   // chunk complete: bias+relu -> Ha (wave-private kh)
                const int nc = group >> 1;
#pragma unroll
                for (int j = 0; j < 2; ++j) {
                    const int col = nc * 256 + wn + j * 16 + l16;
                    const float bj = b1[col];
#pragma unroll
                    for (int i = 0; i < 2; ++i)
#pragma unroll
                        for (int r = 0; r < 4; ++r) {
                            const int row = i * 16 + quad * 4 + r;
                            Ha[wave][row][j * 16 + l16] =
                                f2b(fmaxf(acc1[i][j][r] + bj, 0.f));
                        }
                }
#pragma unroll
                for (int i = 0; i < 2; ++i)
#pragma unroll
                    for (int j = 0; j < 2; ++j) {
                        f32x4 z = {0.f, 0.f, 0.f, 0.f};
                        acc1[i][j] = z;
                    }
            }
        } else {
#pragma unroll
            for (int i = 0; i < 2; ++i)
#pragma unroll
                for (int j = 0; j < 2; ++j) {
                    acc2[i][j] = __builtin_amdgcn_mfma_f32_16x16x32_bf16(af0[i], bf0[j], acc2[i][j], 0, 0, 0);
                    acc2[i][j] = __builtin_amdgcn_mfma_f32_16x16x32_bf16(af1[i], bf1[j], acc2[i][j], 0, 0, 0);
                }
        }
    }

    // ---- fused epilogue: v = acc2 + b2 + Ya; LN2 over the 256-col row ----
    // (plain __syncthreads here: full drain is fine — over-wait only; Ha is
    //  dead so redS/redQ aliasing is safe; QKV bufs for qst=0/1 already landed)
    float mean[2][4], rstd[2][4];

    __syncthreads();   // publish last Ha reads done before red-alias writes

    // pass 1: add bias + residual (from LDS Ya), accumulate row sums
    {
        float sum_[2][4];
#pragma unroll
        for (int i = 0; i < 2; ++i)
#pragma unroll
            for (int r = 0; r < 4; ++r) sum_[i][r] = 0.f;
#pragma unroll
        for (int j = 0; j < 2; ++j) {
            const int col = wn + j * 16 + l16;
            const float bj = b2[col];
#pragma unroll
            for (int i = 0; i < 2; ++i) {
#pragma unroll
                for (int r = 0; r < 4; ++r) {
                    const int row = i * 16 + quad * 4 + r;
                    const float v = acc2[i][j][r] + bj + Ya[row][col];
                    acc2[i][j][r] = v;
                    sum_[i][r] += v;
                }
            }
        }
#pragma unroll
        for (int i = 0; i < 2; ++i)
#pragma unroll
            for (int r = 0; r < 4; ++r) {
                float s = sum_[i][r];
                s += __shfl_xor(s, 1);
                s += __shfl_xor(s, 2);
                s += __shfl_xor(s, 4);
                s += __shfl_xor(s, 8);
                sum_[i][r] = s;
            }
        if (l16 == 0) {
#pragma unroll
            for (int i = 0; i < 2; ++i)
#pragma unroll
                for (int r = 0; r < 4; ++r) redS[wave * 32 + i * 16 + quad * 4 + r] = sum_[i][r];
        }
        __syncthreads();
#pragma unroll
        for (int i = 0; i < 2; ++i)
#pragma unroll
            for (int r = 0; r < 4; ++r) {
                const int rl = i * 16 + quad * 4 + r;
                float s = 0.f;
#pragma unroll
                for (int w = 0; w < 8; ++w) s += redS[w * 32 + rl];
                mean[i][r] = s * (1.0f / 256.0f);
            }
    }

    // pass 2: variance of (v - mean)  (two-pass, matches addln numerics)
    {
        float sq_[2][4];
#pragma unroll
        for (int i = 0; i < 2; ++i)
#pragma unroll
            for (int r = 0; r < 4; ++r) sq_[i][r] = 0.f;
#pragma unroll
        for (int j = 0; j < 2; ++j)
#pragma unroll
            for (int i = 0; i < 2; ++i)
#pragma unroll
                for (int r = 0; r < 4; ++r) {
                    const float d = acc2[i][j][r] - mean[i][r];
                    sq_[i][r] += d * d;
                }
#pragma unroll
        for (int i = 0; i < 2; ++i)
#pragma unroll
            for (int r = 0; r < 4; ++r) {
                float s = sq_[i][r];
                s += __shfl_xor(s, 1);
                s += __shfl_xor(s, 2);
                s += __shfl_xor(s, 4);
                s += __shfl_xor(s, 8);
                sq_[i][r] = s;
            }
        if (l16 == 0) {
#pragma unroll
            for (int i = 0; i < 2; ++i)
#pragma unroll
                for (int r = 0; r < 4; ++r) redQ[wave * 32 + i * 16 + quad * 4 + r] = sq_[i][r];
        }
        __syncthreads();
#pragma unroll
        for (int i = 0; i < 2; ++i)
#pragma unroll
            for (int r = 0; r < 4; ++r) {
                const int rl = i * 16 + quad * 4 + r;
                float s = 0.f;
#pragma unroll
                for (int w = 0; w < 8; ++w) s += redQ[w * 32 + rl];
                rstd[i][r] = rsqrtf(s * (1.0f / 256.0f) + 1e-5f);
            }
    }

    // write y = (v - mean) * rstd * g + be  ->  xout (f32); DO_QKV: + Asf bf16
#pragma unroll
    for (int j = 0; j < 2; ++j) {
        const int col = wn + j * 16 + l16;
        const float gv = g2[col];
        const float bev = be2[col];
#pragma unroll
        for (int i = 0; i < 2; ++i) {
            const int row = bm + i * 16 + quad * 4;
#pragma unroll
            for (int r = 0; r < 4; ++r) {
                const float y = (acc2[i][j][r] - mean[i][r]) * rstd[i][r] * gv + bev;
                xout[(size_t)(row + r) * DD + col] = y;
                if (DO_QKV)
                    Asf[wave][i * 16 + quad * 4 + r][j * 16 + l16] = f2b(y);
            }
        }
    }

    // ---- DO_QKV: next-layer QKV = y @ Wqkv, verbatim scatter epilogue ----
    // Pipelined continuation: bufs for qst=0/1 staged at st=30/31 (global
    // buffer numbering continues: buf = (32+qst)%3).
    if constexpr (DO_QKV) {
        const float av = alpha[qlayer];
        f32x4 acc3[2][2];
#pragma unroll
        for (int i = 0; i < 2; ++i)
#pragma unroll
            for (int j = 0; j < 2; ++j) {
                f32x4 z = {0.f, 0.f, 0.f, 0.f};
                acc3[i][j] = z;
            }

        for (int qst = 0; qst < 12; ++qst) {
            if (qst == 11) pipe_barrier0();
            else pipe_barrier4();

            const int gq = qst + 2;
            if (gq < 12) stageQKV((32 + gq) % 3, gq);

            const int buf = (32 + qst) % 3;
            const int ks = qst & 3;
            bf16x8 af0[2], af1[2], bf0[2], bf1[2];
#pragma unroll
            for (int i = 0; i < 2; ++i) {
                af0[i] = *(const bf16x8*)&Asf[2 * ks][i * 16 + l16][quad * 8];
                af1[i] = *(const bf16x8*)&Asf[2 * ks + 1][i * 16 + l16][quad * 8];
            }
#pragma unroll
            for (int j = 0; j < 2; ++j) {
                bf0[j] = *(const bf16x8*)(Bs0[buf] + (wn + j * 16 + l16) * 32 + quad * 8);
                bf1[j] = *(const bf16x8*)(Bs1[buf] + (wn + j * 16 + l16) * 32 + quad * 8);
            }
#pragma unroll
            for (int i = 0; i < 2; ++i)
#pragma unroll
                for (int j = 0; j < 2; ++j) {
                    acc3[i][j] = __builtin_amdgcn_mfma_f32_16x16x32_bf16(af0[i], bf0[j], acc3[i][j], 0, 0, 0);
                    acc3[i][j] = __builtin_amdgcn_mfma_f32_16x16x32_bf16(af1[i], bf1[j], acc3[i][j], 0, 0, 0);
                }

            if (ks == 3) {   // chunk complete -> scatter (which = chunk)
                const int which = qst >> 2;
#pragma unroll
                for (int j = 0; j < 2; ++j) {
                    const int rem = wn + j * 16 + l16;
                    const float bsv = bqkv[which * 256 + rem];
                    const int h = rem >> 5, d = rem & 31;
#pragma unroll
                    for (int i = 0; i < 2; ++i) {
                        const int row0 = bm + i * 16 + quad * 4;
                        const int bb2 = row0 >> 10, nn0 = row0 & 1023;
                        const size_t bh = (size_t)((bb2 << 3) + h);
                        if (which == 2) {
                            ushort4 pk;
                            pk.x = f2b(acc3[i][j][0] + bsv);
                            pk.y = f2b(acc3[i][j][1] + bsv);
                            pk.z = f2b(acc3[i][j][2] + bsv);
                            pk.w = f2b(acc3[i][j][3] + bsv);
                            *(ushort4*)&Vt[(bh * DK + d) * NN + nn0] = pk;
                        } else {
#pragma unroll
                            for (int r = 0; r < 4; ++r) {
                                const float v = acc3[i][j][r] + bsv;
                                const int nn = nn0 + r;
                                if (which == 0) {
                                    Qa[(bh * NN + nn) * 64 + d] = f2b(v * QSCALE);
                                    if (d < 3)
                                        Qa[(bh * NN + nn) * 64 + 32 + d] =
                                            f2b(av * LOG2E *
                                                coords[(size_t)(bb2 * NN + nn) * 3 + d]);
                                } else {
                                    Ka[(bh * NN + nn) * 64 + d] = f2b(v);
                                }
                            }
                        }
                    }
                }
#pragma unroll
                for (int i = 0; i < 2; ++i)
#pragma unroll
                    for (int j = 0; j < 2; ++j) {
                        f32x4 z = {0.f, 0.f, 0.f, 0.f};
                        acc3[i][j] = z;
                    }
            }
        }
    }
}

// ---------------------------------------------------------------------------
// MFMA flash attention (attn8, R5-verified config — 64-key tiles, LB(256,2)).
// ---------------------------------------------------------------------------
__global__ __launch_bounds__(256, 2) void attn8_kernel(const ushort_t* __restrict__ Qa,
                                                       const ushort_t* __restrict__ Ka,
                                                       const ushort_t* __restrict__ Vt,
                                                       float* __restrict__ aout) {
    const int b = blockIdx.x, h = blockIdx.y, n0 = blockIdx.z * 64;
    const int t = threadIdx.x, wave = t >> 6, lane = t & 63;
    const int quad = lane >> 4, l16 = lane & 15;
    const int bh = b * HH + h;

    __shared__ __align__(16) char smem[56320];
    ushort_t (*Ks)[64][72] = (ushort_t (*)[64][72])smem;             // [4] 36864 B
    ushort_t (*Vs)[32][72] = (ushort_t (*)[32][72])(smem + 36864);   // [4] 18432 B
    float    (*Om)[64][36] = (float (*)[64][36])smem;                // merge alias (36864 B)
    float    (*Lm)[64]     = (float (*)[64])(smem + 55296);          // 1024 B

    // Q fragments: 4 subtiles of 16 q-rows (block's 64 q, held by every wave)
    bf16x8 aq[4][2];
#pragma unroll
    for (int s = 0; s < 4; ++s) {
        const ushort_t* qp = Qa + ((size_t)bh * NN + n0 + s * 16 + l16) * 64 + quad * 8;
        aq[s][0] = *(const bf16x8*)qp;
        aq[s][1] = *(const bf16x8*)(qp + 32);
    }

    const f32x4 z = {0.f, 0.f, 0.f, 0.f};
    f32x4 acc[4][2];
    float lsum[4];
#pragma unroll
    for (int s = 0; s < 4; ++s) { acc[s][0] = z; acc[s][1] = z; lsum[s] = 0.f; }

    const ushort_t* kg = Ka + ((size_t)bh * NN + wave * 256) * 64;
    const ushort_t* vg = Vt + (size_t)bh * DK * NN + wave * 256;

    const int srow = lane >> 3, sch = (lane & 7) * 8;   // staging: 8 rows x 8 chunks

    uint4 kreg[8], vreg[4];
#pragma unroll
    for (int i = 0; i < 8; ++i) kreg[i] = *(const uint4*)(kg + (size_t)(i * 8 + srow) * 64 + sch);
#pragma unroll
    for (int i = 0; i < 4; ++i) vreg[i] = *(const uint4*)(vg + (size_t)(i * 8 + srow) * NN + sch);

    for (int kt = 0; kt < 4; ++kt) {
        // write staged tile (same-wave LDS RAW is in-order: no barrier needed)
#pragma unroll
        for (int i = 0; i < 8; ++i) *(uint4*)&Ks[wave][i * 8 + srow][sch] = kreg[i];
#pragma unroll
        for (int i = 0; i < 4; ++i) *(uint4*)&Vs[wave][i * 8 + srow][sch] = vreg[i];

        // fragment reads (compiler inserts lgkmcnt before first use)
        bf16x8 bk0[4], bk1[4];
#pragma unroll
        for (int jt = 0; jt < 4; ++jt) {
            bk0[jt] = *(const bf16x8*)&Ks[wave][jt * 16 + l16][quad * 8];
            bk1[jt] = *(const bf16x8*)&Ks[wave][jt * 16 + l16][32 + quad * 8];
        }
        bf16x4 vfrag[2][4];
#pragma unroll
        for (int g = 0; g < 2; ++g)
#pragma unroll
            for (int jt = 0; jt < 4; ++jt)
                vfrag[g][jt] = *(const bf16x4*)&Vs[wave][g * 16 + l16][jt * 16 + quad * 4];

        // prefetch next tile's K/V into registers (hidden behind compute)
        if (kt < 3) {
            const ushort_t* kg2 = kg + (size_t)(kt + 1) * 64 * 64;
            const ushort_t* vg2 = vg + (kt + 1) * 64;
#pragma unroll
            for (int i = 0; i < 8; ++i)
                kreg[i] = *(const uint4*)(kg2 + (size_t)(i * 8 + srow) * 64 + sch);
#pragma unroll
            for (int i = 0; i < 4; ++i)
                vreg[i] = *(const uint4*)(vg2 + (size_t)(i * 8 + srow) * NN + sch);
        }

#pragma unroll
        for (int s = 0; s < 4; ++s) {
            // S^T: D[key=quad*4+r (+jt*16)][q=l16]
            f32x4 st[4];
            __builtin_amdgcn_s_setprio(1);
#pragma unroll
            for (int jt = 0; jt < 4; ++jt) {
                st[jt] = __builtin_amdgcn_mfma_f32_16x16x32_bf16(bk0[jt], aq[s][0], z, 0, 0, 0);
                st[jt] = __builtin_amdgcn_mfma_f32_16x16x32_bf16(bk1[jt], aq[s][1], st[jt], 0, 0, 0);
            }
            __builtin_amdgcn_s_setprio(0);
            // exp2 + in-lane pack: B-operand of the K=16 MFMA (n=l16, k=quad*4+j)
            bf16x4 pf[4];
            float ls = 0.f;
#pragma unroll
            for (int jt = 0; jt < 4; ++jt) {
                float e0 = fast_exp2(st[jt][0]);
                float e1 = fast_exp2(st[jt][1]);
                float e2 = fast_exp2(st[jt][2]);
                float e3 = fast_exp2(st[jt][3]);
                ls += (e0 + e1) + (e2 + e3);
                pf[jt][0] = (short)f2b(e0);
                pf[jt][1] = (short)f2b(e1);
                pf[jt][2] = (short)f2b(e2);
                pf[jt][3] = (short)f2b(e3);
            }
            lsum[s] += ls;
            // O^T += V^T . P^T  (K=16 per MFMA)
            __builtin_amdgcn_s_setprio(1);
#pragma unroll
            for (int jt = 0; jt < 4; ++jt) {
                acc[s][0] = mfma16(vfrag[0][jt], pf[jt], acc[s][0]);
                acc[s][1] = mfma16(vfrag[1][jt], pf[jt], acc[s][1]);
            }
            __builtin_amdgcn_s_setprio(0);
        }
    }

    // reduce l across the 4 quads (same q, disjoint key%16 subsets)
#pragma unroll
    for (int s = 0; s < 4; ++s) {
        lsum[s] += __shfl_xor(lsum[s], 16);
        lsum[s] += __shfl_xor(lsum[s], 32);
    }

    __syncthreads();   // all waves done with Ks/Vs — safe to alias as Om/Lm
    if (quad == 0) {
#pragma unroll
        for (int s = 0; s < 4; ++s) Lm[wave][s * 16 + l16] = lsum[s];
    }

    // write O^T partials: Om[wave][q][d]
#pragma unroll
    for (int s = 0; s < 4; ++s) {
        const int q = s * 16 + l16;
#pragma unroll
        for (int g = 0; g < 2; ++g) {
            float4 v = {acc[s][g][0], acc[s][g][1], acc[s][g][2], acc[s][g][3]};
            *(float4*)&Om[wave][q][g * 16 + quad * 4] = v;
        }
    }
    __syncthreads();

    {
        const int q = t >> 2, dseg = (t & 3) * 8;
        const float inv = 1.0f / (Lm[0][q] + Lm[1][q] + Lm[2][q] + Lm[3][q]);
        float* op = aout + (size_t)(b * NN + n0 + q) * DD + h * DK + dseg;
        float4 s0 = {0.f, 0.f, 0.f, 0.f}, s1 = {0.f, 0.f, 0.f, 0.f};
#pragma unroll
        for (int w = 0; w < 4; ++w) {
            float4 a = *(const float4*)&Om[w][q][dseg];
            float4 c = *(const float4*)&Om[w][q][dseg + 4];
            s0.x += a.x; s0.y += a.y; s0.z += a.z; s0.w += a.w;
            s1.x += c.x; s1.y += c.y; s1.z += c.z; s1.w += c.w;
        }
        float4 o0 = {s0.x * inv, s0.y * inv, s0.z * inv, s0.w * inv};
        float4 o1 = {s1.x * inv, s1.y * inv, s1.z * inv, s1.w * inv};
        *(float4*)op = o0;
        *(float4*)(op + 4) = o1;
    }
}

// ---------------------------------------------------------------------------
// launch — workspace ~45.5 MB
// ---------------------------------------------------------------------------
extern "C" void kernel_launch(void* const* d_in, const int* in_sizes, int n_in,
                              void* d_out, int out_size, void* d_ws, size_t ws_size,
                              hipStream_t stream) {
    const float* x      = (const float*)d_in[0];
    const float* coords = (const float*)d_in[1];
    const float* Wq     = (const float*)d_in[2];
    const float* bq     = (const float*)d_in[3];
    const float* Wk     = (const float*)d_in[4];
    const float* bk     = (const float*)d_in[5];
    const float* Wv     = (const float*)d_in[6];
    const float* bv     = (const float*)d_in[7];
    const float* alpha  = (const float*)d_in[8];
    const float* W1     = (const float*)d_in[9];
    const float* b1     = (const float*)d_in[10];
    const float* W2     = (const float*)d_in[11];
    const float* b2     = (const float*)d_in[12];
    const float* g1     = (const float*)d_in[13];
    const float* be1    = (const float*)d_in[14];
    const float* g2     = (const float*)d_in[15];
    const float* be2    = (const float*)d_in[16];

    float* ws = (float*)d_ws;
    float*    xf    = ws;                             // 8 MB
    ushort_t* xb    = (ushort_t*)(ws + 2097152);      // 4 MB
    ushort_t* Qa    = (ushort_t*)(ws + 3145728);      // 8 MB [64 bh][1024][64]
    ushort_t* Ka    = (ushort_t*)(ws + 5242880);      // 8 MB
    ushort_t* Vt    = (ushort_t*)(ws + 7340032);      // 4 MB [64 bh][32][1024]
    float*    aout  = ws + 8388608;                   // 8 MB [8192][256]
    ushort_t* wqkvt = (ushort_t*)(ws + 10485760);     // 1.5 MB  [L][768][256]
    ushort_t* w1t   = (ushort_t*)(ws + 10878976);     // 2 MB    [L][1024][256]
    ushort_t* w2t   = (ushort_t*)(ws + 11403264);     // 2 MB    [L][256][1024]
    float*    bqkv  = ws + 11927552;                  // [L][768]

    // ---- fused weight prep (one dispatch) ----
    prep_kernel<<<NLAYERS * 707, 256, 0, stream>>>(Wq, Wk, Wv, W1, W2, bq, bk, bv,
                                                   wqkvt, w1t, w2t, bqkv);

    // copy-in + layer-invariant Q/K ext init (fused, one dispatch)
    copy_in_kernel<<<ROW_ELEMS / 4 / 256, 256, 0, stream>>>(
        (const float4*)x, (float4*)xf, (ushort4*)xb, ROW_ELEMS / 4, coords, Qa, Ka);

    // layer 0 QKV (standalone; layers 1-3 are fused into the previous ffn)
    mfma_gemm_kernel<2, 64><<<dim3(6, 128), 256, 0, stream>>>(
        xb, wqkvt, bqkv, Qa, Ka, Vt, coords, alpha, 0, 256, 0);

    for (int i = 0; i < NLAYERS; ++i) {
        attn8_kernel<<<dim3(8, 8, 16), 256, 0, stream>>>(Qa, Ka, Vt, aout);

        if (i < NLAYERS - 1) {
            // fused addLN1 + FFN + LN2 + NEXT-LAYER QKV scatter (pipelined)
            ffn_ln_kernel<1><<<MM / 32, 512, 0, stream>>>(
                aout, xf, w1t + (size_t)i * 262144, w2t + (size_t)i * 262144,
                g1 + i * 256, be1 + i * 256, b1 + i * 1024, b2 + i * 256,
                g2 + i * 256, be2 + i * 256, xf,
                wqkvt + (size_t)(i + 1) * 196608, bqkv + (i + 1) * 768,
                coords, alpha, i + 1, Qa, Ka, Vt);
        } else {
            // last layer: no QKV, write d_out
            ffn_ln_kernel<0><<<MM / 32, 512, 0, stream>>>(
                aout, xf, w1t + (size_t)i * 262144, w2t + (size_t)i * 262144,
                g1 + i * 256, be1 + i * 256, b1 + i * 1024, b2 + i * 256,
                g2 + i * 256, be2 + i * 256, (float*)d_out,
                nullptr, nullptr, nullptr, nullptr, 0, nullptr, nullptr, nullptr);
        }
    }
}

// Round 12
// 370.468 us; speedup vs baseline: 1.0777x; 1.0777x over previous
//
#include <hip/hip_runtime.h>
#include <hip/hip_bf16.h>

// Problem constants
#define BB 8
#define NN 1024
#define DD 256
#define HH 8
#define DK 32
#define FFN 1024
#define NLAYERS 4
#define MM (BB * NN)          // 8192 rows
#define ROW_ELEMS (MM * DD)   // 2,097,152

// 1/sqrt(32) * log2(e)  (log2e folded so attention uses native exp2)
#define QSCALE 0.2550655192922103f
#define LOG2E  1.4426950408889634f

typedef unsigned short ushort_t;
typedef __attribute__((ext_vector_type(8))) short bf16x8;
typedef __attribute__((ext_vector_type(4))) short bf16x4;
typedef __attribute__((ext_vector_type(4))) float f32x4;

// K=16 bf16 MFMA: builtin if present on device; inline-asm fallback; host stub.
__device__ __forceinline__ f32x4 mfma16(bf16x4 a, bf16x4 b, f32x4 c) {
#if __has_builtin(__builtin_amdgcn_mfma_f32_16x16x16bf16_1k)
    return __builtin_amdgcn_mfma_f32_16x16x16bf16_1k(a, b, c, 0, 0, 0);
#elif defined(__AMDGCN__)
    f32x4 d;
    asm volatile("v_mfma_f32_16x16x16_bf16 %0, %1, %2, %3"
                 : "=v"(d)
                 : "v"(a), "v"(b), "v"(c));
    return d;
#else
    return c;  // host-pass stub
#endif
}

__device__ __forceinline__ ushort_t f2b(float f) {
    __hip_bfloat16 h = __float2bfloat16(f);
    return *reinterpret_cast<ushort_t*>(&h);
}

// raw v_exp_f32 (input already in log2 domain) — avoids any OCML wrapper
__device__ __forceinline__ float fast_exp2(float x) {
#if __has_builtin(__builtin_amdgcn_exp2f)
    return __builtin_amdgcn_exp2f(x);
#else
    return exp2f(x);
#endif
}

// async global -> LDS, 16 B per lane. LDS dest = wave-uniform base + lane*16B.
__device__ __forceinline__ void async_ld16(const void* g, void* l) {
    __builtin_amdgcn_global_load_lds((const __attribute__((address_space(1))) void*)g,
                                     (__attribute__((address_space(3))) void*)l, 16, 0, 0);
}

// ---------------------------------------------------------------------------
// copy-in + qkext fused: x -> xf (f32) + xb (bf16), float4-vectorized.
// Blocks [0,256) additionally write the layer-invariant Q/K ext columns.
// ---------------------------------------------------------------------------
__global__ __launch_bounds__(256) void copy_in_kernel(const float4* __restrict__ in,
                                                      float4* __restrict__ xf,
                                                      ushort4* __restrict__ xb, int n4,
                                                      const float* __restrict__ coords,
                                                      ushort_t* __restrict__ Qa,
                                                      ushort_t* __restrict__ Ka) {
    int i = blockIdx.x * 256 + threadIdx.x;
    if (i < n4) {
        float4 v = in[i];
        xf[i] = v;
        ushort4 b = {f2b(v.x), f2b(v.y), f2b(v.z), f2b(v.w)};
        xb[i] = b;
    }
    if (blockIdx.x < 256) {
        const int id = blockIdx.x * 256 + threadIdx.x;   // 0..65535 = bh*1024 + n
        const int bh = id >> 10, n = id & 1023;
        const int b = bh >> 3;
        ushort_t buf[32];
#pragma unroll
        for (int d = 0; d < 32; ++d) buf[d] = 0;
        buf[0] = f2b(coords[(size_t)(b * NN + n) * 3 + 0]);
        buf[1] = f2b(coords[(size_t)(b * NN + n) * 3 + 1]);
        buf[2] = f2b(coords[(size_t)(b * NN + n) * 3 + 2]);
        ushort_t* kp = Ka + ((size_t)bh * NN + n) * 64 + 32;
        ushort_t* qp = Qa + ((size_t)bh * NN + n) * 64 + 32;
        const uint4* b4 = (const uint4*)buf;
        uint4 z4 = {0u, 0u, 0u, 0u};
#pragma unroll
        for (int c = 0; c < 4; ++c) {
            *(uint4*)(kp + c * 8) = b4[c];
            *(uint4*)(qp + c * 8) = z4;
        }
    }
}

// ---------------------------------------------------------------------------
// Fused weight prep (one dispatch): 5 transposes + bias concat.
// ---------------------------------------------------------------------------
__global__ __launch_bounds__(256) void prep_kernel(const float* __restrict__ Wq,
                                                   const float* __restrict__ Wk,
                                                   const float* __restrict__ Wv,
                                                   const float* __restrict__ W1,
                                                   const float* __restrict__ W2,
                                                   const float* __restrict__ bq,
                                                   const float* __restrict__ bk,
                                                   const float* __restrict__ bv,
                                                   ushort_t* __restrict__ wqkvt,
                                                   ushort_t* __restrict__ w1t,
                                                   ushort_t* __restrict__ w2t,
                                                   float* __restrict__ bqkv) {
    const int id = blockIdx.x;
    const int layer = id / 707;
    const int r = id % 707;
    const int tid = threadIdx.x;

    if (r >= 704) {  // bias concat: 3 chunks of 256
        const int chunk = r - 704;
        const float* src = (chunk == 0) ? bq : (chunk == 1) ? bk : bv;
        bqkv[layer * 768 + chunk * 256 + tid] = src[layer * 256 + tid];
        return;
    }

    const float* src;
    ushort_t* dst;
    int R, C, x, y;
    if (r < 192) {
        const int w = r >> 6, rr = r & 63;
        src = ((w == 0) ? Wq : (w == 1) ? Wk : Wv) + (size_t)layer * 65536;
        dst = wqkvt + (size_t)layer * 196608 + w * 65536;
        R = 256; C = 256; x = rr & 7; y = rr >> 3;
    } else if (r < 448) {
        const int rr = r - 192;
        src = W1 + (size_t)layer * 262144;
        dst = w1t + (size_t)layer * 262144;
        R = 256; C = 1024; x = rr & 31; y = rr >> 5;
    } else {
        const int rr = r - 448;
        src = W2 + (size_t)layer * 262144;
        dst = w2t + (size_t)layer * 262144;
        R = 1024; C = 256; x = rr & 7; y = rr >> 3;
    }
    const int r0 = y * 32, c0 = x * 32;
    __shared__ float tile[32][33];
    const int tx = tid & 31, ty = tid >> 5;
#pragma unroll
    for (int i = 0; i < 4; ++i)
        tile[ty + 8 * i][tx] = src[(size_t)(r0 + ty + 8 * i) * C + (c0 + tx)];
    __syncthreads();
#pragma unroll
    for (int i = 0; i < 4; ++i)
        dst[(size_t)(c0 + ty + 8 * i) * R + (r0 + tx)] = f2b(tile[tx][ty + 8 * i]);
}

// ---------------------------------------------------------------------------
// MFMA bf16 GEMM, async global_load_lds staging (16B), BK=64, SPLIT-HALF LDS,
// double-buffered (R4-verified). MODE 2: QKV scatter into Qa/Ka/Vt.
// Used ONLY for layer 0's QKV (layers 1-3 fused into ffn_ln).
// ---------------------------------------------------------------------------
template <int MODE, int BM>
__global__ __launch_bounds__(256) void mfma_gemm_kernel(const ushort_t* __restrict__ A,
                                                        const ushort_t* __restrict__ Bt,
                                                        const float* __restrict__ bias,
                                                        void* __restrict__ C0,
                                                        void* __restrict__ C1,
                                                        void* __restrict__ C2,
                                                        const float* __restrict__ coords,
                                                        const float* __restrict__ alpha, int layer,
                                                        int K, int ldc) {
    constexpr int NI = BM / 32;
    __shared__ ushort_t As0[2][BM * 32];
    __shared__ ushort_t As1[2][BM * 32];
    __shared__ ushort_t Bs0[2][128 * 32];
    __shared__ ushort_t Bs1[2][128 * 32];

    const int t    = threadIdx.x;
    const int bm   = blockIdx.y * BM;
    const int bn   = blockIdx.x * 128;
    const int wave = t >> 6, lane = t & 63;
    const int wm   = (wave >> 1) * (BM / 2), wn = (wave & 1) * 64;
    const int quad = lane >> 4, l16 = lane & 15;

    const int srow = t >> 2;          // 0..63
    const int scol = (t & 3) * 8;     // 16B chunk within a 32-ushort half-row

    f32x4 acc[NI][4];
#pragma unroll
    for (int i = 0; i < NI; ++i)
#pragma unroll
        for (int j = 0; j < 4; ++j) {
            f32x4 z = {0.f, 0.f, 0.f, 0.f};
            acc[i][j] = z;
        }

    auto stage = [&](int pb, int k0) {
        // half 0 (k0 .. k0+31)
        async_ld16(A + (size_t)(bm + srow) * K + k0 + scol, As0[pb] + wave * 512);
        if constexpr (BM == 128)
            async_ld16(A + (size_t)(bm + 64 + srow) * K + k0 + scol, As0[pb] + 2048 + wave * 512);
        async_ld16(Bt + (size_t)(bn + srow) * K + k0 + scol, Bs0[pb] + wave * 512);
        async_ld16(Bt + (size_t)(bn + 64 + srow) * K + k0 + scol, Bs0[pb] + 2048 + wave * 512);
        // half 1 (k0+32 .. k0+63)
        async_ld16(A + (size_t)(bm + srow) * K + k0 + 32 + scol, As1[pb] + wave * 512);
        if constexpr (BM == 128)
            async_ld16(A + (size_t)(bm + 64 + srow) * K + k0 + 32 + scol, As1[pb] + 2048 + wave * 512);
        async_ld16(Bt + (size_t)(bn + srow) * K + k0 + 32 + scol, Bs1[pb] + wave * 512);
        async_ld16(Bt + (size_t)(bn + 64 + srow) * K + k0 + 32 + scol, Bs1[pb] + 2048 + wave * 512);
    };

    stage(0, 0);   // prologue
    int pb = 0;
    for (int k0 = 0; k0 < K; k0 += 64, pb ^= 1) {
        __syncthreads();   // drains vmcnt(0): buf[pb] valid; prev compute finished

        if (k0 + 64 < K) stage(pb ^ 1, k0 + 64);   // overlap with compute below

        bf16x8 af0[NI], af1[NI], bf0[4], bf1[4];
#pragma unroll
        for (int i = 0; i < NI; ++i) {
            af0[i] = *(const bf16x8*)(As0[pb] + (wm + i * 16 + l16) * 32 + quad * 8);
            af1[i] = *(const bf16x8*)(As1[pb] + (wm + i * 16 + l16) * 32 + quad * 8);
        }
#pragma unroll
        for (int j = 0; j < 4; ++j) {
            bf0[j] = *(const bf16x8*)(Bs0[pb] + (wn + j * 16 + l16) * 32 + quad * 8);
            bf1[j] = *(const bf16x8*)(Bs1[pb] + (wn + j * 16 + l16) * 32 + quad * 8);
        }
#pragma unroll
        for (int i = 0; i < NI; ++i)
#pragma unroll
            for (int j = 0; j < 4; ++j) {
                acc[i][j] = __builtin_amdgcn_mfma_f32_16x16x32_bf16(af0[i], bf0[j], acc[i][j], 0, 0, 0);
                acc[i][j] = __builtin_amdgcn_mfma_f32_16x16x32_bf16(af1[i], bf1[j], acc[i][j], 0, 0, 0);
            }
    }

    const float av = (MODE == 2) ? alpha[layer] : 0.f;

#pragma unroll
    for (int j = 0; j < 4; ++j) {
        const int col = bn + wn + j * 16 + l16;
        const float bsv = bias[col];
#pragma unroll
        for (int i = 0; i < NI; ++i) {
            const int row0 = bm + wm + i * 16 + quad * 4;
            if (MODE == 2) {
                const int bb2 = row0 >> 10, nn0 = row0 & 1023;
                const int which = col >> 8, rem = col & 255;
                const int h = rem >> 5, d = rem & 31;
                const size_t bh = (size_t)((bb2 << 3) + h);
                if (which == 2) {
                    ushort4 pk;
                    pk.x = f2b(acc[i][j][0] + bsv);
                    pk.y = f2b(acc[i][j][1] + bsv);
                    pk.z = f2b(acc[i][j][2] + bsv);
                    pk.w = f2b(acc[i][j][3] + bsv);
                    *(ushort4*)&((ushort_t*)C2)[(bh * DK + d) * NN + nn0] = pk;
                } else {
#pragma unroll
                    for (int r = 0; r < 4; ++r) {
                        const float v = acc[i][j][r] + bsv;
                        const int nn = nn0 + r;
                        if (which == 0) {
                            ((ushort_t*)C0)[(bh * NN + nn) * 64 + d] = f2b(v * QSCALE);
                            if (d < 3)
                                ((ushort_t*)C0)[(bh * NN + nn) * 64 + 32 + d] =
                                    f2b(av * LOG2E * coords[(size_t)(bb2 * NN + nn) * 3 + d]);
                        } else {
                            ((ushort_t*)C1)[(bh * NN + nn) * 64 + d] = f2b(v);
                            // ext cols pre-filled once (layer-invariant)
                        }
                    }
                }
            } else {
#pragma unroll
                for (int r = 0; r < 4; ++r) {
                    float v = acc[i][j][r] + bsv;
                    if (MODE == 0)
                        ((float*)C0)[(size_t)(row0 + r) * ldc + col] = v;
                    else
                        ((ushort_t*)C0)[(size_t)(row0 + r) * ldc + col] = f2b(fmaxf(v, 0.f));
                }
            }
        }
    }
}

// ---------------------------------------------------------------------------
// FULLY FUSED: addLN1 + FF1 (relu) + FF2 + residual + LN2 [+ next-layer QKV].
// R12: 1024 THREADS (16 waves = 4 waves/SIMD, was 2) — R10's counters showed
// latency-bound lockstep (MfmaUtil 9%, all pipes idle); doubling waves/SIMD
// doubles co-issue in the compute windows and halves per-thread stage loads
// (4->2) so drains shorten. Each wave owns 16 output cols (wn = wave*16,
// j-loop collapsed). Per-output-element MFMA k-order unchanged and LN1 keeps
// the verbatim 64-lane butterfly (16 waves x 2 rows) -> BIT-IDENTICAL math.
// R11's counted-vmcnt pipeline reverted (compiler defeats it; regressed).
// LDS: Ha 16K + Asf 16K + Bs dbuf 64K + Ya 33.3K + red 4K = 133.3 KB.
// ---------------------------------------------------------------------------
template <int DO_QKV>
__global__ __launch_bounds__(1024, 4) void ffn_ln_kernel(const float* __restrict__ aout,
                                                         const float* __restrict__ xfin,
                                                         const ushort_t* __restrict__ W1t,
                                                         const ushort_t* __restrict__ W2t,
                                                         const float* __restrict__ g1,
                                                         const float* __restrict__ be1,
                                                         const float* __restrict__ b1,
                                                         const float* __restrict__ b2,
                                                         const float* __restrict__ g2,
                                                         const float* __restrict__ be2,
                                                         float* __restrict__ xout,
                                                         const ushort_t* __restrict__ Wqkvt,
                                                         const float* __restrict__ bqkv,
                                                         const float* __restrict__ coords,
                                                         const float* __restrict__ alpha, int qlayer,
                                                         ushort_t* __restrict__ Qa,
                                                         ushort_t* __restrict__ Ka,
                                                         ushort_t* __restrict__ Vt) {
    __shared__ ushort_t Ha[8][32][32];      // hidden chunk [kh][row][kc] 16 KB
    __shared__ ushort_t Asf[8][32][32];     // LN1-out / LN2-out bf16     16 KB
    __shared__ ushort_t Bs0[2][256 * 32];   // B k-half 0, dbuf           32 KB
    __shared__ ushort_t Bs1[2][256 * 32];   // B k-half 1, dbuf           32 KB
    __shared__ float Ya[32][260];           // LN1-out f32 (pad->2-way)   33.3 KB
    __shared__ float redS[16][32];          // 2 KB
    __shared__ float redQ[16][32];          // 2 KB

    const int t = threadIdx.x;
    const int bm = blockIdx.x * 32;
    const int wave = t >> 6, lane = t & 63;
    const int quad = lane >> 4, l16 = lane & 15;
    const int wn = wave * 16;           // wave's 16-col slice
    const int scol = (t & 3) * 8;

    // staging: 1024 threads cover the full [256 rows][32 k] half in ONE call
    // (t>>2 in 0..255 = row, (t&3)*8 = 16B chunk); dest = wave*512 + lane*8.
    auto stageB1 = [&](int pb, int nc, int ks) {
        const int brow = nc * 256 + (t >> 2);
        const int k0 = ks * 64;
        async_ld16(W1t + (size_t)brow * 256 + k0 + scol, Bs0[pb] + wave * 512);
        async_ld16(W1t + (size_t)brow * 256 + k0 + 32 + scol, Bs1[pb] + wave * 512);
    };
    auto stageB2 = [&](int pb, int nc, int ks) {
        const int brow = t >> 2;
        const int k0 = nc * 256 + ks * 64;
        async_ld16(W2t + (size_t)brow * 1024 + k0 + scol, Bs0[pb] + wave * 512);
        async_ld16(W2t + (size_t)brow * 1024 + k0 + 32 + scol, Bs1[pb] + wave * 512);
    };
    auto stageFFN = [&](int pb, int st) {
        const int group = st >> 2, ks = st & 3, nc = group >> 1;
        if (!(group & 1)) stageB1(pb, nc, ks);
        else stageB2(pb, nc, ks);
    };
    auto stageQKV = [&](int pb, int qst) {
        const int chunk = qst >> 2, ks = qst & 3;
        const int brow = chunk * 256 + (t >> 2);
        async_ld16(Wqkvt + (size_t)brow * 256 + ks * 64 + scol, Bs0[pb] + wave * 512);
        async_ld16(Wqkvt + (size_t)brow * 256 + ks * 64 + 32 + scol, Bs1[pb] + wave * 512);
    };

    stageFFN(0, 0);   // B1 chunk0 step0 loads overlap phase-0 LN1 compute

    // ---- phase 0: LN1 = VERBATIM addln; 2 rows per wave (16 waves x 2) ----
#pragma unroll
    for (int rr = 0; rr < 2; ++rr) {
        const int row = wave * 2 + rr;
        const size_t base = (size_t)(bm + row) * DD + lane * 4;

        float4 xv = *(const float4*)(xfin + base);
        float4 dl = *(const float4*)(aout + base);
        float v0 = xv.x + dl.x, v1 = xv.y + dl.y, v2 = xv.z + dl.z, v3 = xv.w + dl.w;

        float s = v0 + v1 + v2 + v3;
#pragma unroll
        for (int off = 32; off; off >>= 1) s += __shfl_xor(s, off);
        const float mean = s * (1.0f / 256.0f);

        float d0 = v0 - mean, d1 = v1 - mean, d2 = v2 - mean, d3 = v3 - mean;
        float s2 = d0 * d0 + d1 * d1 + d2 * d2 + d3 * d3;
#pragma unroll
        for (int off = 32; off; off >>= 1) s2 += __shfl_xor(s2, off);
        const float rs = rsqrtf(s2 * (1.0f / 256.0f) + 1e-5f);

        float4 gv = *(const float4*)(g1 + lane * 4);
        float4 bv = *(const float4*)(be1 + lane * 4);
        float y0 = d0 * rs * gv.x + bv.x;
        float y1 = d1 * rs * gv.y + bv.y;
        float y2 = d2 * rs * gv.z + bv.z;
        float y3 = d3 * rs * gv.w + bv.w;

        float4 yv = {y0, y1, y2, y3};
        *(float4*)&Ya[row][lane * 4] = yv;
        const int col0 = lane * 4;
        ushort4 yb = {f2b(y0), f2b(y1), f2b(y2), f2b(y3)};
        *(ushort4*)&Asf[col0 >> 5][row][col0 & 31] = yb;
    }

    f32x4 acc1[2], acc2[2];
#pragma unroll
    for (int i = 0; i < 2; ++i) {
        f32x4 z = {0.f, 0.f, 0.f, 0.f};
        acc1[i] = z;
        acc2[i] = z;
    }

    // ---- 32 interleaved steps: [FF1 chunk nc (4), FF2 part nc (4)] x 4 ----
    int pb = 0;
    for (int st = 0; st < 32; ++st, pb ^= 1) {
        __syncthreads();   // drains vmcnt(0): Bs[pb] valid; (st=0: + Asf/Ya published)
        if (st < 31) stageFFN(pb ^ 1, st + 1);
        else if (DO_QKV) stageQKV(pb ^ 1, 0);   // prefetch QKV chunk0 step0

        const int group = st >> 2, ks = st & 3;
        const bool ff1 = !(group & 1);

        bf16x8 af0[2], af1[2], bf0, bf1;
#pragma unroll
        for (int i = 0; i < 2; ++i) {
            if (ff1) {
                af0[i] = *(const bf16x8*)&Asf[2 * ks][i * 16 + l16][quad * 8];
                af1[i] = *(const bf16x8*)&Asf[2 * ks + 1][i * 16 + l16][quad * 8];
            } else {
                af0[i] = *(const bf16x8*)&Ha[2 * ks][i * 16 + l16][quad * 8];
                af1[i] = *(const bf16x8*)&Ha[2 * ks + 1][i * 16 + l16][quad * 8];
            }
        }
        bf0 = *(const bf16x8*)(Bs0[pb] + (wn + l16) * 32 + quad * 8);
        bf1 = *(const bf16x8*)(Bs1[pb] + (wn + l16) * 32 + quad * 8);

        if (ff1) {
#pragma unroll
            for (int i = 0; i < 2; ++i) {
                acc1[i] = __builtin_amdgcn_mfma_f32_16x16x32_bf16(af0[i], bf0, acc1[i], 0, 0, 0);
                acc1[i] = __builtin_amdgcn_mfma_f32_16x16x32_bf16(af1[i], bf1, acc1[i], 0, 0, 0);
            }
            if (ks == 3) {   // chunk complete: bias+relu -> Ha (disjoint halves)
                const int nc = group >> 1;
                const int col = nc * 256 + wn + l16;
                const float bj = b1[col];
#pragma unroll
                for (int i = 0; i < 2; ++i)
#pragma unroll
                    for (int r = 0; r < 4; ++r) {
                        const int row = i * 16 + quad * 4 + r;
                        Ha[wave >> 1][row][(wave & 1) * 16 + l16] =
                            f2b(fmaxf(acc1[i][r] + bj, 0.f));
                    }
#pragma unroll
                for (int i = 0; i < 2; ++i) {
                    f32x4 z = {0.f, 0.f, 0.f, 0.f};
                    acc1[i] = z;
                }
            }
        } else {
#pragma unroll
            for (int i = 0; i < 2; ++i) {
                acc2[i] = __builtin_amdgcn_mfma_f32_16x16x32_bf16(af0[i], bf0, acc2[i], 0, 0, 0);
                acc2[i] = __builtin_amdgcn_mfma_f32_16x16x32_bf16(af1[i], bf1, acc2[i], 0, 0, 0);
            }
        }
    }

    // ---- fused epilogue: v = acc2 + b2 + Ya; LN2 over the 256-col row ----
    float mean[2][4], rstd[2][4];

    // pass 1: add bias + residual (from LDS Ya), accumulate row sums
    {
        float sum_[2][4];
#pragma unroll
        for (int i = 0; i < 2; ++i)
#pragma unroll
            for (int r = 0; r < 4; ++r) sum_[i][r] = 0.f;
        const int col = wn + l16;
        const float bj = b2[col];
#pragma unroll
        for (int i = 0; i < 2; ++i) {
#pragma unroll
            for (int r = 0; r < 4; ++r) {
                const int row = i * 16 + quad * 4 + r;
                const float v = acc2[i][r] + bj + Ya[row][col];
                acc2[i][r] = v;
                sum_[i][r] += v;
            }
        }
#pragma unroll
        for (int i = 0; i < 2; ++i)
#pragma unroll
            for (int r = 0; r < 4; ++r) {
                float s = sum_[i][r];
                s += __shfl_xor(s, 1);
                s += __shfl_xor(s, 2);
                s += __shfl_xor(s, 4);
                s += __shfl_xor(s, 8);
                sum_[i][r] = s;
            }
        if (l16 == 0) {
#pragma unroll
            for (int i = 0; i < 2; ++i)
#pragma unroll
                for (int r = 0; r < 4; ++r) redS[wave][i * 16 + quad * 4 + r] = sum_[i][r];
        }
        __syncthreads();
#pragma unroll
        for (int i = 0; i < 2; ++i)
#pragma unroll
            for (int r = 0; r < 4; ++r) {
                const int rl = i * 16 + quad * 4 + r;
                float s = 0.f;
#pragma unroll
                for (int w = 0; w < 16; ++w) s += redS[w][rl];
                mean[i][r] = s * (1.0f / 256.0f);
            }
    }

    // pass 2: variance of (v - mean)  (two-pass, matches addln numerics)
    {
        float sq_[2][4];
#pragma unroll
        for (int i = 0; i < 2; ++i)
#pragma unroll
            for (int r = 0; r < 4; ++r) {
                const float d = acc2[i][r] - mean[i][r];
                sq_[i][r] = d * d;
            }
#pragma unroll
        for (int i = 0; i < 2; ++i)
#pragma unroll
            for (int r = 0; r < 4; ++r) {
                float s = sq_[i][r];
                s += __shfl_xor(s, 1);
                s += __shfl_xor(s, 2);
                s += __shfl_xor(s, 4);
                s += __shfl_xor(s, 8);
                sq_[i][r] = s;
            }
        if (l16 == 0) {
#pragma unroll
            for (int i = 0; i < 2; ++i)
#pragma unroll
                for (int r = 0; r < 4; ++r) redQ[wave][i * 16 + quad * 4 + r] = sq_[i][r];
        }
        __syncthreads();
#pragma unroll
        for (int i = 0; i < 2; ++i)
#pragma unroll
            for (int r = 0; r < 4; ++r) {
                const int rl = i * 16 + quad * 4 + r;
                float s = 0.f;
#pragma unroll
                for (int w = 0; w < 16; ++w) s += redQ[w][rl];
                rstd[i][r] = rsqrtf(s * (1.0f / 256.0f) + 1e-5f);
            }
    }

    // write y = (v - mean) * rstd * g + be  ->  xout (f32); DO_QKV: + Asf bf16
    {
        const int col = wn + l16;
        const float gv = g2[col];
        const float bev = be2[col];
#pragma unroll
        for (int i = 0; i < 2; ++i) {
            const int row = bm + i * 16 + quad * 4;
#pragma unroll
            for (int r = 0; r < 4; ++r) {
                const float y = (acc2[i][r] - mean[i][r]) * rstd[i][r] * gv + bev;
                xout[(size_t)(row + r) * DD + col] = y;
                if (DO_QKV)
                    Asf[wave >> 1][i * 16 + quad * 4 + r][(wave & 1) * 16 + l16] = f2b(y);
            }
        }
    }

    // ---- DO_QKV: next-layer QKV = y @ Wqkv, verbatim scatter epilogue ----
    if constexpr (DO_QKV) {
        const float av = alpha[qlayer];
        f32x4 acc3[2];
#pragma unroll
        for (int i = 0; i < 2; ++i) {
            f32x4 z = {0.f, 0.f, 0.f, 0.f};
            acc3[i] = z;
        }

        for (int qst = 0; qst < 12; ++qst, pb ^= 1) {
            __syncthreads();   // drains vmcnt(0): Bs[pb] valid; (qst=0: + Asf y published)
            if (qst < 11) stageQKV(pb ^ 1, qst + 1);

            const int ks = qst & 3;
            bf16x8 af0[2], af1[2], bf0, bf1;
#pragma unroll
            for (int i = 0; i < 2; ++i) {
                af0[i] = *(const bf16x8*)&Asf[2 * ks][i * 16 + l16][quad * 8];
                af1[i] = *(const bf16x8*)&Asf[2 * ks + 1][i * 16 + l16][quad * 8];
            }
            bf0 = *(const bf16x8*)(Bs0[pb] + (wn + l16) * 32 + quad * 8);
            bf1 = *(const bf16x8*)(Bs1[pb] + (wn + l16) * 32 + quad * 8);
#pragma unroll
            for (int i = 0; i < 2; ++i) {
                acc3[i] = __builtin_amdgcn_mfma_f32_16x16x32_bf16(af0[i], bf0, acc3[i], 0, 0, 0);
                acc3[i] = __builtin_amdgcn_mfma_f32_16x16x32_bf16(af1[i], bf1, acc3[i], 0, 0, 0);
            }

            if (ks == 3) {   // chunk complete -> scatter (which = chunk)
                const int which = qst >> 2;
                const int rem = wn + l16;
                const float bsv = bqkv[which * 256 + rem];
                const int h = rem >> 5, d = rem & 31;
#pragma unroll
                for (int i = 0; i < 2; ++i) {
                    const int row0 = bm + i * 16 + quad * 4;
                    const int bb2 = row0 >> 10, nn0 = row0 & 1023;
                    const size_t bh = (size_t)((bb2 << 3) + h);
                    if (which == 2) {
                        ushort4 pk;
                        pk.x = f2b(acc3[i][0] + bsv);
                        pk.y = f2b(acc3[i][1] + bsv);
                        pk.z = f2b(acc3[i][2] + bsv);
                        pk.w = f2b(acc3[i][3] + bsv);
                        *(ushort4*)&Vt[(bh * DK + d) * NN + nn0] = pk;
                    } else {
#pragma unroll
                        for (int r = 0; r < 4; ++r) {
                            const float v = acc3[i][r] + bsv;
                            const int nn = nn0 + r;
                            if (which == 0) {
                                Qa[(bh * NN + nn) * 64 + d] = f2b(v * QSCALE);
                                if (d < 3)
                                    Qa[(bh * NN + nn) * 64 + 32 + d] =
                                        f2b(av * LOG2E *
                                            coords[(size_t)(bb2 * NN + nn) * 3 + d]);
                            } else {
                                Ka[(bh * NN + nn) * 64 + d] = f2b(v);
                            }
                        }
                    }
                }
#pragma unroll
                for (int i = 0; i < 2; ++i) {
                    f32x4 z = {0.f, 0.f, 0.f, 0.f};
                    acc3[i] = z;
                }
            }
        }
    }
}

// ---------------------------------------------------------------------------
// MFMA flash attention (attn8, R5-verified config — 64-key tiles, LB(256,2)).
// ---------------------------------------------------------------------------
__global__ __launch_bounds__(256, 2) void attn8_kernel(const ushort_t* __restrict__ Qa,
                                                       const ushort_t* __restrict__ Ka,
                                                       const ushort_t* __restrict__ Vt,
                                                       float* __restrict__ aout) {
    const int b = blockIdx.x, h = blockIdx.y, n0 = blockIdx.z * 64;
    const int t = threadIdx.x, wave = t >> 6, lane = t & 63;
    const int quad = lane >> 4, l16 = lane & 15;
    const int bh = b * HH + h;

    __shared__ __align__(16) char smem[56320];
    ushort_t (*Ks)[64][72] = (ushort_t (*)[64][72])smem;             // [4] 36864 B
    ushort_t (*Vs)[32][72] = (ushort_t (*)[32][72])(smem + 36864);   // [4] 18432 B
    float    (*Om)[64][36] = (float (*)[64][36])smem;                // merge alias (36864 B)
    float    (*Lm)[64]     = (float (*)[64])(smem + 55296);          // 1024 B

    // Q fragments: 4 subtiles of 16 q-rows (block's 64 q, held by every wave)
    bf16x8 aq[4][2];
#pragma unroll
    for (int s = 0; s < 4; ++s) {
        const ushort_t* qp = Qa + ((size_t)bh * NN + n0 + s * 16 + l16) * 64 + quad * 8;
        aq[s][0] = *(const bf16x8*)qp;
        aq[s][1] = *(const bf16x8*)(qp + 32);
    }

    const f32x4 z = {0.f, 0.f, 0.f, 0.f};
    f32x4 acc[4][2];
    float lsum[4];
#pragma unroll
    for (int s = 0; s < 4; ++s) { acc[s][0] = z; acc[s][1] = z; lsum[s] = 0.f; }

    const ushort_t* kg = Ka + ((size_t)bh * NN + wave * 256) * 64;
    const ushort_t* vg = Vt + (size_t)bh * DK * NN + wave * 256;

    const int srow = lane >> 3, sch = (lane & 7) * 8;   // staging: 8 rows x 8 chunks

    uint4 kreg[8], vreg[4];
#pragma unroll
    for (int i = 0; i < 8; ++i) kreg[i] = *(const uint4*)(kg + (size_t)(i * 8 + srow) * 64 + sch);
#pragma unroll
    for (int i = 0; i < 4; ++i) vreg[i] = *(const uint4*)(vg + (size_t)(i * 8 + srow) * NN + sch);

    for (int kt = 0; kt < 4; ++kt) {
        // write staged tile (same-wave LDS RAW is in-order: no barrier needed)
#pragma unroll
        for (int i = 0; i < 8; ++i) *(uint4*)&Ks[wave][i * 8 + srow][sch] = kreg[i];
#pragma unroll
        for (int i = 0; i < 4; ++i) *(uint4*)&Vs[wave][i * 8 + srow][sch] = vreg[i];

        // fragment reads (compiler inserts lgkmcnt before first use)
        bf16x8 bk0[4], bk1[4];
#pragma unroll
        for (int jt = 0; jt < 4; ++jt) {
            bk0[jt] = *(const bf16x8*)&Ks[wave][jt * 16 + l16][quad * 8];
            bk1[jt] = *(const bf16x8*)&Ks[wave][jt * 16 + l16][32 + quad * 8];
        }
        bf16x4 vfrag[2][4];
#pragma unroll
        for (int g = 0; g < 2; ++g)
#pragma unroll
            for (int jt = 0; jt < 4; ++jt)
                vfrag[g][jt] = *(const bf16x4*)&Vs[wave][g * 16 + l16][jt * 16 + quad * 4];

        // prefetch next tile's K/V into registers (hidden behind compute)
        if (kt < 3) {
            const ushort_t* kg2 = kg + (size_t)(kt + 1) * 64 * 64;
            const ushort_t* vg2 = vg + (kt + 1) * 64;
#pragma unroll
            for (int i = 0; i < 8; ++i)
                kreg[i] = *(const uint4*)(kg2 + (size_t)(i * 8 + srow) * 64 + sch);
#pragma unroll
            for (int i = 0; i < 4; ++i)
                vreg[i] = *(const uint4*)(vg2 + (size_t)(i * 8 + srow) * NN + sch);
        }

#pragma unroll
        for (int s = 0; s < 4; ++s) {
            // S^T: D[key=quad*4+r (+jt*16)][q=l16]
            f32x4 st[4];
            __builtin_amdgcn_s_setprio(1);
#pragma unroll
            for (int jt = 0; jt < 4; ++jt) {
                st[jt] = __builtin_amdgcn_mfma_f32_16x16x32_bf16(bk0[jt], aq[s][0], z, 0, 0, 0);
                st[jt] = __builtin_amdgcn_mfma_f32_16x16x32_bf16(bk1[jt], aq[s][1], st[jt], 0, 0, 0);
            }
            __builtin_amdgcn_s_setprio(0);
            // exp2 + in-lane pack: B-operand of the K=16 MFMA (n=l16, k=quad*4+j)
            bf16x4 pf[4];
            float ls = 0.f;
#pragma unroll
            for (int jt = 0; jt < 4; ++jt) {
                float e0 = fast_exp2(st[jt][0]);
                float e1 = fast_exp2(st[jt][1]);
                float e2 = fast_exp2(st[jt][2]);
                float e3 = fast_exp2(st[jt][3]);
                ls += (e0 + e1) + (e2 + e3);
                pf[jt][0] = (short)f2b(e0);
                pf[jt][1] = (short)f2b(e1);
                pf[jt][2] = (short)f2b(e2);
                pf[jt][3] = (short)f2b(e3);
            }
            lsum[s] += ls;
            // O^T += V^T . P^T  (K=16 per MFMA)
            __builtin_amdgcn_s_setprio(1);
#pragma unroll
            for (int jt = 0; jt < 4; ++jt) {
                acc[s][0] = mfma16(vfrag[0][jt], pf[jt], acc[s][0]);
                acc[s][1] = mfma16(vfrag[1][jt], pf[jt], acc[s][1]);
            }
            __builtin_amdgcn_s_setprio(0);
        }
    }

    // reduce l across the 4 quads (same q, disjoint key%16 subsets)
#pragma unroll
    for (int s = 0; s < 4; ++s) {
        lsum[s] += __shfl_xor(lsum[s], 16);
        lsum[s] += __shfl_xor(lsum[s], 32);
    }

    __syncthreads();   // all waves done with Ks/Vs — safe to alias as Om/Lm
    if (quad == 0) {
#pragma unroll
        for (int s = 0; s < 4; ++s) Lm[wave][s * 16 + l16] = lsum[s];
    }

    // write O^T partials: Om[wave][q][d]
#pragma unroll
    for (int s = 0; s < 4; ++s) {
        const int q = s * 16 + l16;
#pragma unroll
        for (int g = 0; g < 2; ++g) {
            float4 v = {acc[s][g][0], acc[s][g][1], acc[s][g][2], acc[s][g][3]};
            *(float4*)&Om[wave][q][g * 16 + quad * 4] = v;
        }
    }
    __syncthreads();

    {
        const int q = t >> 2, dseg = (t & 3) * 8;
        const float inv = 1.0f / (Lm[0][q] + Lm[1][q] + Lm[2][q] + Lm[3][q]);
        float* op = aout + (size_t)(b * NN + n0 + q) * DD + h * DK + dseg;
        float4 s0 = {0.f, 0.f, 0.f, 0.f}, s1 = {0.f, 0.f, 0.f, 0.f};
#pragma unroll
        for (int w = 0; w < 4; ++w) {
            float4 a = *(const float4*)&Om[w][q][dseg];
            float4 c = *(const float4*)&Om[w][q][dseg + 4];
            s0.x += a.x; s0.y += a.y; s0.z += a.z; s0.w += a.w;
            s1.x += c.x; s1.y += c.y; s1.z += c.z; s1.w += c.w;
        }
        float4 o0 = {s0.x * inv, s0.y * inv, s0.z * inv, s0.w * inv};
        float4 o1 = {s1.x * inv, s1.y * inv, s1.z * inv, s1.w * inv};
        *(float4*)op = o0;
        *(float4*)(op + 4) = o1;
    }
}

// ---------------------------------------------------------------------------
// launch — workspace ~45.5 MB
// ---------------------------------------------------------------------------
extern "C" void kernel_launch(void* const* d_in, const int* in_sizes, int n_in,
                              void* d_out, int out_size, void* d_ws, size_t ws_size,
                              hipStream_t stream) {
    const float* x      = (const float*)d_in[0];
    const float* coords = (const float*)d_in[1];
    const float* Wq     = (const float*)d_in[2];
    const float* bq     = (const float*)d_in[3];
    const float* Wk     = (const float*)d_in[4];
    const float* bk     = (const float*)d_in[5];
    const float* Wv     = (const float*)d_in[6];
    const float* bv     = (const float*)d_in[7];
    const float* alpha  = (const float*)d_in[8];
    const float* W1     = (const float*)d_in[9];
    const float* b1     = (const float*)d_in[10];
    const float* W2     = (const float*)d_in[11];
    const float* b2     = (const float*)d_in[12];
    const float* g1     = (const float*)d_in[13];
    const float* be1    = (const float*)d_in[14];
    const float* g2     = (const float*)d_in[15];
    const float* be2    = (const float*)d_in[16];

    float* ws = (float*)d_ws;
    float*    xf    = ws;                             // 8 MB
    ushort_t* xb    = (ushort_t*)(ws + 2097152);      // 4 MB
    ushort_t* Qa    = (ushort_t*)(ws + 3145728);      // 8 MB [64 bh][1024][64]
    ushort_t* Ka    = (ushort_t*)(ws + 5242880);      // 8 MB
    ushort_t* Vt    = (ushort_t*)(ws + 7340032);      // 4 MB [64 bh][32][1024]
    float*    aout  = ws + 8388608;                   // 8 MB [8192][256]
    ushort_t* wqkvt = (ushort_t*)(ws + 10485760);     // 1.5 MB  [L][768][256]
    ushort_t* w1t   = (ushort_t*)(ws + 10878976);     // 2 MB    [L][1024][256]
    ushort_t* w2t   = (ushort_t*)(ws + 11403264);     // 2 MB    [L][256][1024]
    float*    bqkv  = ws + 11927552;                  // [L][768]

    // ---- fused weight prep (one dispatch) ----
    prep_kernel<<<NLAYERS * 707, 256, 0, stream>>>(Wq, Wk, Wv, W1, W2, bq, bk, bv,
                                                   wqkvt, w1t, w2t, bqkv);

    // copy-in + layer-invariant Q/K ext init (fused, one dispatch)
    copy_in_kernel<<<ROW_ELEMS / 4 / 256, 256, 0, stream>>>(
        (const float4*)x, (float4*)xf, (ushort4*)xb, ROW_ELEMS / 4, coords, Qa, Ka);

    // layer 0 QKV (standalone; layers 1-3 are fused into the previous ffn)
    mfma_gemm_kernel<2, 64><<<dim3(6, 128), 256, 0, stream>>>(
        xb, wqkvt, bqkv, Qa, Ka, Vt, coords, alpha, 0, 256, 0);

    for (int i = 0; i < NLAYERS; ++i) {
        attn8_kernel<<<dim3(8, 8, 16), 256, 0, stream>>>(Qa, Ka, Vt, aout);

        if (i < NLAYERS - 1) {
            // fused addLN1 + FFN + LN2 + NEXT-LAYER QKV scatter (1024 threads)
            ffn_ln_kernel<1><<<MM / 32, 1024, 0, stream>>>(
                aout, xf, w1t + (size_t)i * 262144, w2t + (size_t)i * 262144,
                g1 + i * 256, be1 + i * 256, b1 + i * 1024, b2 + i * 256,
                g2 + i * 256, be2 + i * 256, xf,
                wqkvt + (size_t)(i + 1) * 196608, bqkv + (i + 1) * 768,
                coords, alpha, i + 1, Qa, Ka, Vt);
        } else {
            // last layer: no QKV, write d_out
            ffn_ln_kernel<0><<<MM / 32, 1024, 0, stream>>>(
                aout, xf, w1t + (size_t)i * 262144, w2t + (size_t)i * 262144,
                g1 + i * 256, be1 + i * 256, b1 + i * 1024, b2 + i * 256,
                g2 + i * 256, be2 + i * 256, (float*)d_out,
                nullptr, nullptr, nullptr, nullptr, 0, nullptr, nullptr, nullptr);
        }
    }
}

// Round 13
// 359.561 us; speedup vs baseline: 1.1104x; 1.0303x over previous
//
#include <hip/hip_runtime.h>
#include <hip/hip_bf16.h>

// Problem constants
#define BB 8
#define NN 1024
#define DD 256
#define HH 8
#define DK 32
#define FFN 1024
#define NLAYERS 4
#define MM (BB * NN)          // 8192 rows
#define ROW_ELEMS (MM * DD)   // 2,097,152

// 1/sqrt(32) * log2(e)  (log2e folded so attention uses native exp2)
#define QSCALE 0.2550655192922103f
#define LOG2E  1.4426950408889634f

typedef unsigned short ushort_t;
typedef __attribute__((ext_vector_type(8))) short bf16x8;
typedef __attribute__((ext_vector_type(4))) short bf16x4;
typedef __attribute__((ext_vector_type(4))) float f32x4;

// K=16 bf16 MFMA: builtin if present on device; inline-asm fallback; host stub.
__device__ __forceinline__ f32x4 mfma16(bf16x4 a, bf16x4 b, f32x4 c) {
#if __has_builtin(__builtin_amdgcn_mfma_f32_16x16x16bf16_1k)
    return __builtin_amdgcn_mfma_f32_16x16x16bf16_1k(a, b, c, 0, 0, 0);
#elif defined(__AMDGCN__)
    f32x4 d;
    asm volatile("v_mfma_f32_16x16x16_bf16 %0, %1, %2, %3"
                 : "=v"(d)
                 : "v"(a), "v"(b), "v"(c));
    return d;
#else
    return c;  // host-pass stub
#endif
}

__device__ __forceinline__ ushort_t f2b(float f) {
    __hip_bfloat16 h = __float2bfloat16(f);
    return *reinterpret_cast<ushort_t*>(&h);
}

// raw v_exp_f32 (input already in log2 domain) — avoids any OCML wrapper
__device__ __forceinline__ float fast_exp2(float x) {
#if __has_builtin(__builtin_amdgcn_exp2f)
    return __builtin_amdgcn_exp2f(x);
#else
    return exp2f(x);
#endif
}

// async global -> LDS, 16 B per lane. LDS dest = wave-uniform base + lane*16B.
__device__ __forceinline__ void async_ld16(const void* g, void* l) {
    __builtin_amdgcn_global_load_lds((const __attribute__((address_space(1))) void*)g,
                                     (__attribute__((address_space(3))) void*)l, 16, 0, 0);
}

// ---------------------------------------------------------------------------
// SETUP (one dispatch): blocks [0,2828) = weight prep (5 transposes + bias
// concat, verbatim prep_kernel); blocks [2828,4876) = copy-in x -> xf/xb +
// layer-invariant Q/K ext init (verbatim copy_in fused variant). The two
// halves touch disjoint data; branch is block-uniform.
// ---------------------------------------------------------------------------
#define PREP_BLOCKS (NLAYERS * 707)      // 2828
#define COPY_BLOCKS (ROW_ELEMS / 4 / 256)  // 2048
__global__ __launch_bounds__(256) void setup_kernel(const float* __restrict__ Wq,
                                                    const float* __restrict__ Wk,
                                                    const float* __restrict__ Wv,
                                                    const float* __restrict__ W1,
                                                    const float* __restrict__ W2,
                                                    const float* __restrict__ bq,
                                                    const float* __restrict__ bk,
                                                    const float* __restrict__ bv,
                                                    ushort_t* __restrict__ wqkvt,
                                                    ushort_t* __restrict__ w1t,
                                                    ushort_t* __restrict__ w2t,
                                                    float* __restrict__ bqkv,
                                                    const float4* __restrict__ in,
                                                    float4* __restrict__ xf,
                                                    ushort4* __restrict__ xb,
                                                    const float* __restrict__ coords,
                                                    ushort_t* __restrict__ Qa,
                                                    ushort_t* __restrict__ Ka) {
    const int tid = threadIdx.x;
    __shared__ float tile[32][33];

    if (blockIdx.x < PREP_BLOCKS) {
        const int id = blockIdx.x;
        const int layer = id / 707;
        const int r = id % 707;

        if (r >= 704) {  // bias concat: 3 chunks of 256
            const int chunk = r - 704;
            const float* src = (chunk == 0) ? bq : (chunk == 1) ? bk : bv;
            bqkv[layer * 768 + chunk * 256 + tid] = src[layer * 256 + tid];
            return;
        }

        const float* src;
        ushort_t* dst;
        int R, C, x, y;
        if (r < 192) {
            const int w = r >> 6, rr = r & 63;
            src = ((w == 0) ? Wq : (w == 1) ? Wk : Wv) + (size_t)layer * 65536;
            dst = wqkvt + (size_t)layer * 196608 + w * 65536;
            R = 256; C = 256; x = rr & 7; y = rr >> 3;
        } else if (r < 448) {
            const int rr = r - 192;
            src = W1 + (size_t)layer * 262144;
            dst = w1t + (size_t)layer * 262144;
            R = 256; C = 1024; x = rr & 31; y = rr >> 5;
        } else {
            const int rr = r - 448;
            src = W2 + (size_t)layer * 262144;
            dst = w2t + (size_t)layer * 262144;
            R = 1024; C = 256; x = rr & 7; y = rr >> 3;
        }
        const int r0 = y * 32, c0 = x * 32;
        const int tx = tid & 31, ty = tid >> 5;
#pragma unroll
        for (int i = 0; i < 4; ++i)
            tile[ty + 8 * i][tx] = src[(size_t)(r0 + ty + 8 * i) * C + (c0 + tx)];
        __syncthreads();
#pragma unroll
        for (int i = 0; i < 4; ++i)
            dst[(size_t)(c0 + ty + 8 * i) * R + (r0 + tx)] = f2b(tile[tx][ty + 8 * i]);
    } else {
        const int cb = blockIdx.x - PREP_BLOCKS;
        const int i = cb * 256 + tid;
        {
            float4 v = in[i];
            xf[i] = v;
            ushort4 b = {f2b(v.x), f2b(v.y), f2b(v.z), f2b(v.w)};
            xb[i] = b;
        }
        if (cb < 256) {
            const int id = cb * 256 + tid;   // 0..65535 = bh*1024 + n
            const int bh = id >> 10, n = id & 1023;
            const int b = bh >> 3;
            ushort_t buf[32];
#pragma unroll
            for (int d = 0; d < 32; ++d) buf[d] = 0;
            buf[0] = f2b(coords[(size_t)(b * NN + n) * 3 + 0]);
            buf[1] = f2b(coords[(size_t)(b * NN + n) * 3 + 1]);
            buf[2] = f2b(coords[(size_t)(b * NN + n) * 3 + 2]);
            ushort_t* kp = Ka + ((size_t)bh * NN + n) * 64 + 32;
            ushort_t* qp = Qa + ((size_t)bh * NN + n) * 64 + 32;
            const uint4* b4 = (const uint4*)buf;
            uint4 z4 = {0u, 0u, 0u, 0u};
#pragma unroll
            for (int c = 0; c < 4; ++c) {
                *(uint4*)(kp + c * 8) = b4[c];
                *(uint4*)(qp + c * 8) = z4;
            }
        }
    }
}

// ---------------------------------------------------------------------------
// MFMA bf16 GEMM, async global_load_lds staging (16B), BK=64, SPLIT-HALF LDS,
// double-buffered (R4-verified). MODE 2: QKV scatter into Qa/Ka/Vt.
// Used ONLY for layer 0's QKV (layers 1-3 fused into ffn_ln).
// ---------------------------------------------------------------------------
template <int MODE, int BM>
__global__ __launch_bounds__(256) void mfma_gemm_kernel(const ushort_t* __restrict__ A,
                                                        const ushort_t* __restrict__ Bt,
                                                        const float* __restrict__ bias,
                                                        void* __restrict__ C0,
                                                        void* __restrict__ C1,
                                                        void* __restrict__ C2,
                                                        const float* __restrict__ coords,
                                                        const float* __restrict__ alpha, int layer,
                                                        int K, int ldc) {
    constexpr int NI = BM / 32;
    __shared__ ushort_t As0[2][BM * 32];
    __shared__ ushort_t As1[2][BM * 32];
    __shared__ ushort_t Bs0[2][128 * 32];
    __shared__ ushort_t Bs1[2][128 * 32];

    const int t    = threadIdx.x;
    const int bm   = blockIdx.y * BM;
    const int bn   = blockIdx.x * 128;
    const int wave = t >> 6, lane = t & 63;
    const int wm   = (wave >> 1) * (BM / 2), wn = (wave & 1) * 64;
    const int quad = lane >> 4, l16 = lane & 15;

    const int srow = t >> 2;          // 0..63
    const int scol = (t & 3) * 8;     // 16B chunk within a 32-ushort half-row

    f32x4 acc[NI][4];
#pragma unroll
    for (int i = 0; i < NI; ++i)
#pragma unroll
        for (int j = 0; j < 4; ++j) {
            f32x4 z = {0.f, 0.f, 0.f, 0.f};
            acc[i][j] = z;
        }

    auto stage = [&](int pb, int k0) {
        // half 0 (k0 .. k0+31)
        async_ld16(A + (size_t)(bm + srow) * K + k0 + scol, As0[pb] + wave * 512);
        if constexpr (BM == 128)
            async_ld16(A + (size_t)(bm + 64 + srow) * K + k0 + scol, As0[pb] + 2048 + wave * 512);
        async_ld16(Bt + (size_t)(bn + srow) * K + k0 + scol, Bs0[pb] + wave * 512);
        async_ld16(Bt + (size_t)(bn + 64 + srow) * K + k0 + scol, Bs0[pb] + 2048 + wave * 512);
        // half 1 (k0+32 .. k0+63)
        async_ld16(A + (size_t)(bm + srow) * K + k0 + 32 + scol, As1[pb] + wave * 512);
        if constexpr (BM == 128)
            async_ld16(A + (size_t)(bm + 64 + srow) * K + k0 + 32 + scol, As1[pb] + 2048 + wave * 512);
        async_ld16(Bt + (size_t)(bn + srow) * K + k0 + 32 + scol, Bs1[pb] + wave * 512);
        async_ld16(Bt + (size_t)(bn + 64 + srow) * K + k0 + 32 + scol, Bs1[pb] + 2048 + wave * 512);
    };

    stage(0, 0);   // prologue
    int pb = 0;
    for (int k0 = 0; k0 < K; k0 += 64, pb ^= 1) {
        __syncthreads();   // drains vmcnt(0): buf[pb] valid; prev compute finished

        if (k0 + 64 < K) stage(pb ^ 1, k0 + 64);   // overlap with compute below

        bf16x8 af0[NI], af1[NI], bf0[4], bf1[4];
#pragma unroll
        for (int i = 0; i < NI; ++i) {
            af0[i] = *(const bf16x8*)(As0[pb] + (wm + i * 16 + l16) * 32 + quad * 8);
            af1[i] = *(const bf16x8*)(As1[pb] + (wm + i * 16 + l16) * 32 + quad * 8);
        }
#pragma unroll
        for (int j = 0; j < 4; ++j) {
            bf0[j] = *(const bf16x8*)(Bs0[pb] + (wn + j * 16 + l16) * 32 + quad * 8);
            bf1[j] = *(const bf16x8*)(Bs1[pb] + (wn + j * 16 + l16) * 32 + quad * 8);
        }
#pragma unroll
        for (int i = 0; i < NI; ++i)
#pragma unroll
            for (int j = 0; j < 4; ++j) {
                acc[i][j] = __builtin_amdgcn_mfma_f32_16x16x32_bf16(af0[i], bf0[j], acc[i][j], 0, 0, 0);
                acc[i][j] = __builtin_amdgcn_mfma_f32_16x16x32_bf16(af1[i], bf1[j], acc[i][j], 0, 0, 0);
            }
    }

    const float av = (MODE == 2) ? alpha[layer] : 0.f;

#pragma unroll
    for (int j = 0; j < 4; ++j) {
        const int col = bn + wn + j * 16 + l16;
        const float bsv = bias[col];
#pragma unroll
        for (int i = 0; i < NI; ++i) {
            const int row0 = bm + wm + i * 16 + quad * 4;
            if (MODE == 2) {
                const int bb2 = row0 >> 10, nn0 = row0 & 1023;
                const int which = col >> 8, rem = col & 255;
                const int h = rem >> 5, d = rem & 31;
                const size_t bh = (size_t)((bb2 << 3) + h);
                if (which == 2) {
                    ushort4 pk;
                    pk.x = f2b(acc[i][j][0] + bsv);
                    pk.y = f2b(acc[i][j][1] + bsv);
                    pk.z = f2b(acc[i][j][2] + bsv);
                    pk.w = f2b(acc[i][j][3] + bsv);
                    *(ushort4*)&((ushort_t*)C2)[(bh * DK + d) * NN + nn0] = pk;
                } else {
#pragma unroll
                    for (int r = 0; r < 4; ++r) {
                        const float v = acc[i][j][r] + bsv;
                        const int nn = nn0 + r;
                        if (which == 0) {
                            ((ushort_t*)C0)[(bh * NN + nn) * 64 + d] = f2b(v * QSCALE);
                            if (d < 3)
                                ((ushort_t*)C0)[(bh * NN + nn) * 64 + 32 + d] =
                                    f2b(av * LOG2E * coords[(size_t)(bb2 * NN + nn) * 3 + d]);
                        } else {
                            ((ushort_t*)C1)[(bh * NN + nn) * 64 + d] = f2b(v);
                            // ext cols pre-filled once (layer-invariant)
                        }
                    }
                }
            } else {
#pragma unroll
                for (int r = 0; r < 4; ++r) {
                    float v = acc[i][j][r] + bsv;
                    if (MODE == 0)
                        ((float*)C0)[(size_t)(row0 + r) * ldc + col] = v;
                    else
                        ((ushort_t*)C0)[(size_t)(row0 + r) * ldc + col] = f2b(fmaxf(v, 0.f));
                }
            }
        }
    }
}

// ---------------------------------------------------------------------------
// FULLY FUSED: addLN1 + FF1 (relu) + FF2 + residual + LN2 [+ next-layer QKV].
// R10-VERIFIED version (512 threads, 8 waves, dbuf staging). R11's counted
// vmcnt (compiler defeats it) and R12's 1024-thread variant (block-global
// barrier: intra-block waves can't hide the drain) both regressed — revert.
// BM=32 rows/block, grid 256 (1/CU).
// LDS: Ha 16K + Asf 16K + Bs dbuf 64K + Ya 33.3K + red 2K = 130.5 KB.
// ---------------------------------------------------------------------------
template <int DO_QKV>
__global__ __launch_bounds__(512) void ffn_ln_kernel(const float* __restrict__ aout,
                                                     const float* __restrict__ xfin,
                                                     const ushort_t* __restrict__ W1t,
                                                     const ushort_t* __restrict__ W2t,
                                                     const float* __restrict__ g1,
                                                     const float* __restrict__ be1,
                                                     const float* __restrict__ b1,
                                                     const float* __restrict__ b2,
                                                     const float* __restrict__ g2,
                                                     const float* __restrict__ be2,
                                                     float* __restrict__ xout,
                                                     const ushort_t* __restrict__ Wqkvt,
                                                     const float* __restrict__ bqkv,
                                                     const float* __restrict__ coords,
                                                     const float* __restrict__ alpha, int qlayer,
                                                     ushort_t* __restrict__ Qa,
                                                     ushort_t* __restrict__ Ka,
                                                     ushort_t* __restrict__ Vt) {
    __shared__ ushort_t Ha[8][32][32];      // hidden chunk [kh][row][kc] 16 KB
    __shared__ ushort_t Asf[8][32][32];     // LN1-out / LN2-out bf16     16 KB
    __shared__ ushort_t Bs0[2][256 * 32];   // B k-half 0, dbuf           32 KB
    __shared__ ushort_t Bs1[2][256 * 32];   // B k-half 1, dbuf           32 KB
    __shared__ float Ya[32][260];           // LN1-out f32 (pad->2-way)   33.3 KB
    __shared__ float redS[8][32];
    __shared__ float redQ[8][32];

    const int t = threadIdx.x;
    const int bm = blockIdx.x * 32;
    const int wave = t >> 6, lane = t & 63;
    const int quad = lane >> 4, l16 = lane & 15;
    const int wn = wave * 32;           // wave's 32-col slice
    const int scol = (t & 3) * 8;

    auto stageB1 = [&](int pb, int nc, int ks) {
        const int nbase = nc * 256;
        const int k0 = ks * 64;
#pragma unroll
        for (int c = 0; c < 2; ++c) {
            const int brow = nbase + c * 128 + (t >> 2);
            async_ld16(W1t + (size_t)brow * 256 + k0 + scol, Bs0[pb] + c * 4096 + wave * 512);
            async_ld16(W1t + (size_t)brow * 256 + k0 + 32 + scol, Bs1[pb] + c * 4096 + wave * 512);
        }
    };
    auto stageB2 = [&](int pb, int nc, int ks) {
        const int k0 = nc * 256 + ks * 64;
#pragma unroll
        for (int c = 0; c < 2; ++c) {
            const int brow = c * 128 + (t >> 2);
            async_ld16(W2t + (size_t)brow * 1024 + k0 + scol, Bs0[pb] + c * 4096 + wave * 512);
            async_ld16(W2t + (size_t)brow * 1024 + k0 + 32 + scol, Bs1[pb] + c * 4096 + wave * 512);
        }
    };
    auto stage = [&](int pb, int st) {
        const int group = st >> 2, ks = st & 3, nc = group >> 1;
        if (!(group & 1)) stageB1(pb, nc, ks);
        else stageB2(pb, nc, ks);
    };
    auto stageQKV = [&](int pb, int qst) {
        const int chunk = qst >> 2, ks = qst & 3;
#pragma unroll
        for (int c = 0; c < 2; ++c) {
            const int brow = chunk * 256 + c * 128 + (t >> 2);
            async_ld16(Wqkvt + (size_t)brow * 256 + ks * 64 + scol, Bs0[pb] + c * 4096 + wave * 512);
            async_ld16(Wqkvt + (size_t)brow * 256 + ks * 64 + 32 + scol, Bs1[pb] + c * 4096 + wave * 512);
        }
    };

    stage(0, 0);   // B1 chunk0 step0 loads overlap phase-0 LN1 compute

    // ---- phase 0: LN1 = addln replica; 4 rows per wave ----
#pragma unroll
    for (int rr = 0; rr < 4; ++rr) {
        const int row = wave * 4 + rr;
        const size_t base = (size_t)(bm + row) * DD + lane * 4;

        float4 xv = *(const float4*)(xfin + base);
        float4 dl = *(const float4*)(aout + base);
        float v0 = xv.x + dl.x, v1 = xv.y + dl.y, v2 = xv.z + dl.z, v3 = xv.w + dl.w;

        float s = v0 + v1 + v2 + v3;
#pragma unroll
        for (int off = 32; off; off >>= 1) s += __shfl_xor(s, off);
        const float mean = s * (1.0f / 256.0f);

        float d0 = v0 - mean, d1 = v1 - mean, d2 = v2 - mean, d3 = v3 - mean;
        float s2 = d0 * d0 + d1 * d1 + d2 * d2 + d3 * d3;
#pragma unroll
        for (int off = 32; off; off >>= 1) s2 += __shfl_xor(s2, off);
        const float rs = rsqrtf(s2 * (1.0f / 256.0f) + 1e-5f);

        float4 gv = *(const float4*)(g1 + lane * 4);
        float4 bv = *(const float4*)(be1 + lane * 4);
        float y0 = d0 * rs * gv.x + bv.x;
        float y1 = d1 * rs * gv.y + bv.y;
        float y2 = d2 * rs * gv.z + bv.z;
        float y3 = d3 * rs * gv.w + bv.w;

        float4 yv = {y0, y1, y2, y3};
        *(float4*)&Ya[row][lane * 4] = yv;
        const int col0 = lane * 4;
        ushort4 yb = {f2b(y0), f2b(y1), f2b(y2), f2b(y3)};
        *(ushort4*)&Asf[col0 >> 5][row][col0 & 31] = yb;
    }

    f32x4 acc1[2][2], acc2[2][2];
#pragma unroll
    for (int i = 0; i < 2; ++i)
#pragma unroll
        for (int j = 0; j < 2; ++j) {
            f32x4 z = {0.f, 0.f, 0.f, 0.f};
            acc1[i][j] = z;
            acc2[i][j] = z;
        }

    // ---- 32 interleaved steps: [FF1 chunk nc (4), FF2 part nc (4)] x 4 ----
    int pb = 0;
    for (int st = 0; st < 32; ++st, pb ^= 1) {
        __syncthreads();   // drains vmcnt(0): Bs[pb] valid; (st=0: + Asf/Ya published)
        if (st < 31) stage(pb ^ 1, st + 1);
        else if (DO_QKV) stageQKV(pb ^ 1, 0);   // prefetch QKV chunk0 step0

        const int group = st >> 2, ks = st & 3;
        const bool ff1 = !(group & 1);

        bf16x8 af0[2], af1[2], bf0[2], bf1[2];
#pragma unroll
        for (int i = 0; i < 2; ++i) {
            if (ff1) {
                af0[i] = *(const bf16x8*)&Asf[2 * ks][i * 16 + l16][quad * 8];
                af1[i] = *(const bf16x8*)&Asf[2 * ks + 1][i * 16 + l16][quad * 8];
            } else {
                af0[i] = *(const bf16x8*)&Ha[2 * ks][i * 16 + l16][quad * 8];
                af1[i] = *(const bf16x8*)&Ha[2 * ks + 1][i * 16 + l16][quad * 8];
            }
        }
#pragma unroll
        for (int j = 0; j < 2; ++j) {
            bf0[j] = *(const bf16x8*)(Bs0[pb] + (wn + j * 16 + l16) * 32 + quad * 8);
            bf1[j] = *(const bf16x8*)(Bs1[pb] + (wn + j * 16 + l16) * 32 + quad * 8);
        }

        if (ff1) {
#pragma unroll
            for (int i = 0; i < 2; ++i)
#pragma unroll
                for (int j = 0; j < 2; ++j) {
                    acc1[i][j] = __builtin_amdgcn_mfma_f32_16x16x32_bf16(af0[i], bf0[j], acc1[i][j], 0, 0, 0);
                    acc1[i][j] = __builtin_amdgcn_mfma_f32_16x16x32_bf16(af1[i], bf1[j], acc1[i][j], 0, 0, 0);
                }
            if (ks == 3) {   // chunk complete: bias+relu -> Ha (wave-private kh)
                const int nc = group >> 1;
#pragma unroll
                for (int j = 0; j < 2; ++j) {
                    const int col = nc * 256 + wn + j * 16 + l16;
                    const float bj = b1[col];
#pragma unroll
                    for (int i = 0; i < 2; ++i)
#pragma unroll
                        for (int r = 0; r < 4; ++r) {
                            const int row = i * 16 + quad * 4 + r;
                            Ha[wave][row][j * 16 + l16] =
                                f2b(fmaxf(acc1[i][j][r] + bj, 0.f));
                        }
                }
#pragma unroll
                for (int i = 0; i < 2; ++i)
#pragma unroll
                    for (int j = 0; j < 2; ++j) {
                        f32x4 z = {0.f, 0.f, 0.f, 0.f};
                        acc1[i][j] = z;
                    }
            }
        } else {
#pragma unroll
            for (int i = 0; i < 2; ++i)
#pragma unroll
                for (int j = 0; j < 2; ++j) {
                    acc2[i][j] = __builtin_amdgcn_mfma_f32_16x16x32_bf16(af0[i], bf0[j], acc2[i][j], 0, 0, 0);
                    acc2[i][j] = __builtin_amdgcn_mfma_f32_16x16x32_bf16(af1[i], bf1[j], acc2[i][j], 0, 0, 0);
                }
        }
    }

    // ---- fused epilogue: v = acc2 + b2 + Ya; LN2 over the 256-col row ----
    float mean[2][4], rstd[2][4];

    // pass 1: add bias + residual (from LDS Ya), accumulate row sums
    {
        float sum_[2][4];
#pragma unroll
        for (int i = 0; i < 2; ++i)
#pragma unroll
            for (int r = 0; r < 4; ++r) sum_[i][r] = 0.f;
#pragma unroll
        for (int j = 0; j < 2; ++j) {
            const int col = wn + j * 16 + l16;
            const float bj = b2[col];
#pragma unroll
            for (int i = 0; i < 2; ++i) {
#pragma unroll
                for (int r = 0; r < 4; ++r) {
                    const int row = i * 16 + quad * 4 + r;
                    const float v = acc2[i][j][r] + bj + Ya[row][col];
                    acc2[i][j][r] = v;
                    sum_[i][r] += v;
                }
            }
        }
#pragma unroll
        for (int i = 0; i < 2; ++i)
#pragma unroll
            for (int r = 0; r < 4; ++r) {
                float s = sum_[i][r];
                s += __shfl_xor(s, 1);
                s += __shfl_xor(s, 2);
                s += __shfl_xor(s, 4);
                s += __shfl_xor(s, 8);
                sum_[i][r] = s;
            }
        if (l16 == 0) {
#pragma unroll
            for (int i = 0; i < 2; ++i)
#pragma unroll
                for (int r = 0; r < 4; ++r) redS[wave][i * 16 + quad * 4 + r] = sum_[i][r];
        }
        __syncthreads();
#pragma unroll
        for (int i = 0; i < 2; ++i)
#pragma unroll
            for (int r = 0; r < 4; ++r) {
                const int rl = i * 16 + quad * 4 + r;
                float s = 0.f;
#pragma unroll
                for (int w = 0; w < 8; ++w) s += redS[w][rl];
                mean[i][r] = s * (1.0f / 256.0f);
            }
    }

    // pass 2: variance of (v - mean)  (two-pass, matches addln numerics)
    {
        float sq_[2][4];
#pragma unroll
        for (int i = 0; i < 2; ++i)
#pragma unroll
            for (int r = 0; r < 4; ++r) sq_[i][r] = 0.f;
#pragma unroll
        for (int j = 0; j < 2; ++j)
#pragma unroll
            for (int i = 0; i < 2; ++i)
#pragma unroll
                for (int r = 0; r < 4; ++r) {
                    const float d = acc2[i][j][r] - mean[i][r];
                    sq_[i][r] += d * d;
                }
#pragma unroll
        for (int i = 0; i < 2; ++i)
#pragma unroll
            for (int r = 0; r < 4; ++r) {
                float s = sq_[i][r];
                s += __shfl_xor(s, 1);
                s += __shfl_xor(s, 2);
                s += __shfl_xor(s, 4);
                s += __shfl_xor(s, 8);
                sq_[i][r] = s;
            }
        if (l16 == 0) {
#pragma unroll
            for (int i = 0; i < 2; ++i)
#pragma unroll
                for (int r = 0; r < 4; ++r) redQ[wave][i * 16 + quad * 4 + r] = sq_[i][r];
        }
        __syncthreads();
#pragma unroll
        for (int i = 0; i < 2; ++i)
#pragma unroll
            for (int r = 0; r < 4; ++r) {
                const int rl = i * 16 + quad * 4 + r;
                float s = 0.f;
#pragma unroll
                for (int w = 0; w < 8; ++w) s += redQ[w][rl];
                rstd[i][r] = rsqrtf(s * (1.0f / 256.0f) + 1e-5f);
            }
    }

    // write y = (v - mean) * rstd * g + be  ->  xout (f32); DO_QKV: + Asf bf16
#pragma unroll
    for (int j = 0; j < 2; ++j) {
        const int col = wn + j * 16 + l16;
        const float gv = g2[col];
        const float bev = be2[col];
#pragma unroll
        for (int i = 0; i < 2; ++i) {
            const int row = bm + i * 16 + quad * 4;
#pragma unroll
            for (int r = 0; r < 4; ++r) {
                const float y = (acc2[i][j][r] - mean[i][r]) * rstd[i][r] * gv + bev;
                xout[(size_t)(row + r) * DD + col] = y;
                if (DO_QKV)
                    Asf[wave][i * 16 + quad * 4 + r][j * 16 + l16] = f2b(y);
            }
        }
    }

    // ---- DO_QKV: next-layer QKV = y @ Wqkv, verbatim scatter epilogue ----
    if constexpr (DO_QKV) {
        const float av = alpha[qlayer];
        f32x4 acc3[2][2];
#pragma unroll
        for (int i = 0; i < 2; ++i)
#pragma unroll
            for (int j = 0; j < 2; ++j) {
                f32x4 z = {0.f, 0.f, 0.f, 0.f};
                acc3[i][j] = z;
            }

        for (int qst = 0; qst < 12; ++qst, pb ^= 1) {
            __syncthreads();   // drains vmcnt(0): Bs[pb] valid; (qst=0: + Asf y published)
            if (qst < 11) stageQKV(pb ^ 1, qst + 1);

            const int ks = qst & 3;
            bf16x8 af0[2], af1[2], bf0[2], bf1[2];
#pragma unroll
            for (int i = 0; i < 2; ++i) {
                af0[i] = *(const bf16x8*)&Asf[2 * ks][i * 16 + l16][quad * 8];
                af1[i] = *(const bf16x8*)&Asf[2 * ks + 1][i * 16 + l16][quad * 8];
            }
#pragma unroll
            for (int j = 0; j < 2; ++j) {
                bf0[j] = *(const bf16x8*)(Bs0[pb] + (wn + j * 16 + l16) * 32 + quad * 8);
                bf1[j] = *(const bf16x8*)(Bs1[pb] + (wn + j * 16 + l16) * 32 + quad * 8);
            }
#pragma unroll
            for (int i = 0; i < 2; ++i)
#pragma unroll
                for (int j = 0; j < 2; ++j) {
                    acc3[i][j] = __builtin_amdgcn_mfma_f32_16x16x32_bf16(af0[i], bf0[j], acc3[i][j], 0, 0, 0);
                    acc3[i][j] = __builtin_amdgcn_mfma_f32_16x16x32_bf16(af1[i], bf1[j], acc3[i][j], 0, 0, 0);
                }

            if (ks == 3) {   // chunk complete -> scatter (which = chunk)
                const int which = qst >> 2;
#pragma unroll
                for (int j = 0; j < 2; ++j) {
                    const int rem = wn + j * 16 + l16;
                    const float bsv = bqkv[which * 256 + rem];
                    const int h = rem >> 5, d = rem & 31;
#pragma unroll
                    for (int i = 0; i < 2; ++i) {
                        const int row0 = bm + i * 16 + quad * 4;
                        const int bb2 = row0 >> 10, nn0 = row0 & 1023;
                        const size_t bh = (size_t)((bb2 << 3) + h);
                        if (which == 2) {
                            ushort4 pk;
                            pk.x = f2b(acc3[i][j][0] + bsv);
                            pk.y = f2b(acc3[i][j][1] + bsv);
                            pk.z = f2b(acc3[i][j][2] + bsv);
                            pk.w = f2b(acc3[i][j][3] + bsv);
                            *(ushort4*)&Vt[(bh * DK + d) * NN + nn0] = pk;
                        } else {
#pragma unroll
                            for (int r = 0; r < 4; ++r) {
                                const float v = acc3[i][j][r] + bsv;
                                const int nn = nn0 + r;
                                if (which == 0) {
                                    Qa[(bh * NN + nn) * 64 + d] = f2b(v * QSCALE);
                                    if (d < 3)
                                        Qa[(bh * NN + nn) * 64 + 32 + d] =
                                            f2b(av * LOG2E *
                                                coords[(size_t)(bb2 * NN + nn) * 3 + d]);
                                } else {
                                    Ka[(bh * NN + nn) * 64 + d] = f2b(v);
                                }
                            }
                        }
                    }
                }
#pragma unroll
                for (int i = 0; i < 2; ++i)
#pragma unroll
                    for (int j = 0; j < 2; ++j) {
                        f32x4 z = {0.f, 0.f, 0.f, 0.f};
                        acc3[i][j] = z;
                    }
            }
        }
    }
}

// ---------------------------------------------------------------------------
// MFMA flash attention (attn8, R5-verified config — 64-key tiles, LB(256,2)).
// ---------------------------------------------------------------------------
__global__ __launch_bounds__(256, 2) void attn8_kernel(const ushort_t* __restrict__ Qa,
                                                       const ushort_t* __restrict__ Ka,
                                                       const ushort_t* __restrict__ Vt,
                                                       float* __restrict__ aout) {
    const int b = blockIdx.x, h = blockIdx.y, n0 = blockIdx.z * 64;
    const int t = threadIdx.x, wave = t >> 6, lane = t & 63;
    const int quad = lane >> 4, l16 = lane & 15;
    const int bh = b * HH + h;

    __shared__ __align__(16) char smem[56320];
    ushort_t (*Ks)[64][72] = (ushort_t (*)[64][72])smem;             // [4] 36864 B
    ushort_t (*Vs)[32][72] = (ushort_t (*)[32][72])(smem + 36864);   // [4] 18432 B
    float    (*Om)[64][36] = (float (*)[64][36])smem;                // merge alias (36864 B)
    float    (*Lm)[64]     = (float (*)[64])(smem + 55296);          // 1024 B

    // Q fragments: 4 subtiles of 16 q-rows (block's 64 q, held by every wave)
    bf16x8 aq[4][2];
#pragma unroll
    for (int s = 0; s < 4; ++s) {
        const ushort_t* qp = Qa + ((size_t)bh * NN + n0 + s * 16 + l16) * 64 + quad * 8;
        aq[s][0] = *(const bf16x8*)qp;
        aq[s][1] = *(const bf16x8*)(qp + 32);
    }

    const f32x4 z = {0.f, 0.f, 0.f, 0.f};
    f32x4 acc[4][2];
    float lsum[4];
#pragma unroll
    for (int s = 0; s < 4; ++s) { acc[s][0] = z; acc[s][1] = z; lsum[s] = 0.f; }

    const ushort_t* kg = Ka + ((size_t)bh * NN + wave * 256) * 64;
    const ushort_t* vg = Vt + (size_t)bh * DK * NN + wave * 256;

    const int srow = lane >> 3, sch = (lane & 7) * 8;   // staging: 8 rows x 8 chunks

    uint4 kreg[8], vreg[4];
#pragma unroll
    for (int i = 0; i < 8; ++i) kreg[i] = *(const uint4*)(kg + (size_t)(i * 8 + srow) * 64 + sch);
#pragma unroll
    for (int i = 0; i < 4; ++i) vreg[i] = *(const uint4*)(vg + (size_t)(i * 8 + srow) * NN + sch);

    for (int kt = 0; kt < 4; ++kt) {
        // write staged tile (same-wave LDS RAW is in-order: no barrier needed)
#pragma unroll
        for (int i = 0; i < 8; ++i) *(uint4*)&Ks[wave][i * 8 + srow][sch] = kreg[i];
#pragma unroll
        for (int i = 0; i < 4; ++i) *(uint4*)&Vs[wave][i * 8 + srow][sch] = vreg[i];

        // fragment reads (compiler inserts lgkmcnt before first use)
        bf16x8 bk0[4], bk1[4];
#pragma unroll
        for (int jt = 0; jt < 4; ++jt) {
            bk0[jt] = *(const bf16x8*)&Ks[wave][jt * 16 + l16][quad * 8];
            bk1[jt] = *(const bf16x8*)&Ks[wave][jt * 16 + l16][32 + quad * 8];
        }
        bf16x4 vfrag[2][4];
#pragma unroll
        for (int g = 0; g < 2; ++g)
#pragma unroll
            for (int jt = 0; jt < 4; ++jt)
                vfrag[g][jt] = *(const bf16x4*)&Vs[wave][g * 16 + l16][jt * 16 + quad * 4];

        // prefetch next tile's K/V into registers (hidden behind compute)
        if (kt < 3) {
            const ushort_t* kg2 = kg + (size_t)(kt + 1) * 64 * 64;
            const ushort_t* vg2 = vg + (kt + 1) * 64;
#pragma unroll
            for (int i = 0; i < 8; ++i)
                kreg[i] = *(const uint4*)(kg2 + (size_t)(i * 8 + srow) * 64 + sch);
#pragma unroll
            for (int i = 0; i < 4; ++i)
                vreg[i] = *(const uint4*)(vg2 + (size_t)(i * 8 + srow) * NN + sch);
        }

#pragma unroll
        for (int s = 0; s < 4; ++s) {
            // S^T: D[key=quad*4+r (+jt*16)][q=l16]
            f32x4 st[4];
            __builtin_amdgcn_s_setprio(1);
#pragma unroll
            for (int jt = 0; jt < 4; ++jt) {
                st[jt] = __builtin_amdgcn_mfma_f32_16x16x32_bf16(bk0[jt], aq[s][0], z, 0, 0, 0);
                st[jt] = __builtin_amdgcn_mfma_f32_16x16x32_bf16(bk1[jt], aq[s][1], st[jt], 0, 0, 0);
            }
            __builtin_amdgcn_s_setprio(0);
            // exp2 + in-lane pack: B-operand of the K=16 MFMA (n=l16, k=quad*4+j)
            bf16x4 pf[4];
            float ls = 0.f;
#pragma unroll
            for (int jt = 0; jt < 4; ++jt) {
                float e0 = fast_exp2(st[jt][0]);
                float e1 = fast_exp2(st[jt][1]);
                float e2 = fast_exp2(st[jt][2]);
                float e3 = fast_exp2(st[jt][3]);
                ls += (e0 + e1) + (e2 + e3);
                pf[jt][0] = (short)f2b(e0);
                pf[jt][1] = (short)f2b(e1);
                pf[jt][2] = (short)f2b(e2);
                pf[jt][3] = (short)f2b(e3);
            }
            lsum[s] += ls;
            // O^T += V^T . P^T  (K=16 per MFMA)
            __builtin_amdgcn_s_setprio(1);
#pragma unroll
            for (int jt = 0; jt < 4; ++jt) {
                acc[s][0] = mfma16(vfrag[0][jt], pf[jt], acc[s][0]);
                acc[s][1] = mfma16(vfrag[1][jt], pf[jt], acc[s][1]);
            }
            __builtin_amdgcn_s_setprio(0);
        }
    }

    // reduce l across the 4 quads (same q, disjoint key%16 subsets)
#pragma unroll
    for (int s = 0; s < 4; ++s) {
        lsum[s] += __shfl_xor(lsum[s], 16);
        lsum[s] += __shfl_xor(lsum[s], 32);
    }

    __syncthreads();   // all waves done with Ks/Vs — safe to alias as Om/Lm
    if (quad == 0) {
#pragma unroll
        for (int s = 0; s < 4; ++s) Lm[wave][s * 16 + l16] = lsum[s];
    }

    // write O^T partials: Om[wave][q][d]
#pragma unroll
    for (int s = 0; s < 4; ++s) {
        const int q = s * 16 + l16;
#pragma unroll
        for (int g = 0; g < 2; ++g) {
            float4 v = {acc[s][g][0], acc[s][g][1], acc[s][g][2], acc[s][g][3]};
            *(float4*)&Om[wave][q][g * 16 + quad * 4] = v;
        }
    }
    __syncthreads();

    {
        const int q = t >> 2, dseg = (t & 3) * 8;
        const float inv = 1.0f / (Lm[0][q] + Lm[1][q] + Lm[2][q] + Lm[3][q]);
        float* op = aout + (size_t)(b * NN + n0 + q) * DD + h * DK + dseg;
        float4 s0 = {0.f, 0.f, 0.f, 0.f}, s1 = {0.f, 0.f, 0.f, 0.f};
#pragma unroll
        for (int w = 0; w < 4; ++w) {
            float4 a = *(const float4*)&Om[w][q][dseg];
            float4 c = *(const float4*)&Om[w][q][dseg + 4];
            s0.x += a.x; s0.y += a.y; s0.z += a.z; s0.w += a.w;
            s1.x += c.x; s1.y += c.y; s1.z += c.z; s1.w += c.w;
        }
        float4 o0 = {s0.x * inv, s0.y * inv, s0.z * inv, s0.w * inv};
        float4 o1 = {s1.x * inv, s1.y * inv, s1.z * inv, s1.w * inv};
        *(float4*)op = o0;
        *(float4*)(op + 4) = o1;
    }
}

// ---------------------------------------------------------------------------
// launch — workspace ~45.5 MB
// ---------------------------------------------------------------------------
extern "C" void kernel_launch(void* const* d_in, const int* in_sizes, int n_in,
                              void* d_out, int out_size, void* d_ws, size_t ws_size,
                              hipStream_t stream) {
    const float* x      = (const float*)d_in[0];
    const float* coords = (const float*)d_in[1];
    const float* Wq     = (const float*)d_in[2];
    const float* bq     = (const float*)d_in[3];
    const float* Wk     = (const float*)d_in[4];
    const float* bk     = (const float*)d_in[5];
    const float* Wv     = (const float*)d_in[6];
    const float* bv     = (const float*)d_in[7];
    const float* alpha  = (const float*)d_in[8];
    const float* W1     = (const float*)d_in[9];
    const float* b1     = (const float*)d_in[10];
    const float* W2     = (const float*)d_in[11];
    const float* b2     = (const float*)d_in[12];
    const float* g1     = (const float*)d_in[13];
    const float* be1    = (const float*)d_in[14];
    const float* g2     = (const float*)d_in[15];
    const float* be2    = (const float*)d_in[16];

    float* ws = (float*)d_ws;
    float*    xf    = ws;                             // 8 MB
    ushort_t* xb    = (ushort_t*)(ws + 2097152);      // 4 MB
    ushort_t* Qa    = (ushort_t*)(ws + 3145728);      // 8 MB [64 bh][1024][64]
    ushort_t* Ka    = (ushort_t*)(ws + 5242880);      // 8 MB
    ushort_t* Vt    = (ushort_t*)(ws + 7340032);      // 4 MB [64 bh][32][1024]
    float*    aout  = ws + 8388608;                   // 8 MB [8192][256]
    ushort_t* wqkvt = (ushort_t*)(ws + 10485760);     // 1.5 MB  [L][768][256]
    ushort_t* w1t   = (ushort_t*)(ws + 10878976);     // 2 MB    [L][1024][256]
    ushort_t* w2t   = (ushort_t*)(ws + 11403264);     // 2 MB    [L][256][1024]
    float*    bqkv  = ws + 11927552;                  // [L][768]

    // ---- setup: weight prep + copy-in + qkext (ONE dispatch) ----
    setup_kernel<<<PREP_BLOCKS + COPY_BLOCKS, 256, 0, stream>>>(
        Wq, Wk, Wv, W1, W2, bq, bk, bv, wqkvt, w1t, w2t, bqkv,
        (const float4*)x, (float4*)xf, (ushort4*)xb, coords, Qa, Ka);

    // layer 0 QKV (standalone; layers 1-3 are fused into the previous ffn)
    mfma_gemm_kernel<2, 64><<<dim3(6, 128), 256, 0, stream>>>(
        xb, wqkvt, bqkv, Qa, Ka, Vt, coords, alpha, 0, 256, 0);

    for (int i = 0; i < NLAYERS; ++i) {
        attn8_kernel<<<dim3(8, 8, 16), 256, 0, stream>>>(Qa, Ka, Vt, aout);

        if (i < NLAYERS - 1) {
            // fused addLN1 + FFN + LN2 + NEXT-LAYER QKV scatter (R10-verified)
            ffn_ln_kernel<1><<<MM / 32, 512, 0, stream>>>(
                aout, xf, w1t + (size_t)i * 262144, w2t + (size_t)i * 262144,
                g1 + i * 256, be1 + i * 256, b1 + i * 1024, b2 + i * 256,
                g2 + i * 256, be2 + i * 256, xf,
                wqkvt + (size_t)(i + 1) * 196608, bqkv + (i + 1) * 768,
                coords, alpha, i + 1, Qa, Ka, Vt);
        } else {
            // last layer: no QKV, write d_out
            ffn_ln_kernel<0><<<MM / 32, 512, 0, stream>>>(
                aout, xf, w1t + (size_t)i * 262144, w2t + (size_t)i * 262144,
                g1 + i * 256, be1 + i * 256, b1 + i * 1024, b2 + i * 256,
                g2 + i * 256, be2 + i * 256, (float*)d_out,
                nullptr, nullptr, nullptr, nullptr, 0, nullptr, nullptr, nullptr);
        }
    }
}